// Round 1
// baseline (5725.781 us; speedup 1.0000x reference)
//
#include <hip/hip_runtime.h>
#include <hip/hip_bf16.h>

using bf16 = __hip_bfloat16;

// ---------------- problem constants ----------------
static constexpr int Bb = 2, Cc = 128, Hh = 48, Ww = 96;
static constexpr int HW = Hh * Ww;            // 4608
static constexpr int DD = 49, Nn = Bb * DD;   // 98
static constexpr int H2 = 24, W2 = 48, HW2 = H2 * W2; // 1152

// ---------------- workspace layout (bytes) ----------------
static constexpr size_t off_wT1a = 0;                       // 128*9*96*4   = 442368
static constexpr size_t off_wT1b = 442368;                  // 442368
static constexpr size_t off_wT2  = 884736;                  // 96*9*128*4   = 442368
static constexpr size_t off_wT3  = 1327104;                 // 128*9*128*4  = 589824
static constexpr size_t off_wT4  = 1916928;                 // 128*9*64*4   = 294912
static constexpr size_t off_wT5  = 2211840;                 // 2*2*64*2*2*32*4 = 131072
static constexpr size_t off_wT6  = 2342912;                 // 32*9*1*4     = 1152
static constexpr size_t off_f1b  = 2344192;                 // bf16 f1: 1179648*2 = 2359296
static constexpr size_t off_y1a  = 4703488;                 // f32: 2*96*4608*4 = 3538944
static constexpr size_t off_stats= 8242432;                 // 5 layers * 2048B
static constexpr size_t off_f2s  = 8252672;                 // bf16: 98*128*4608*2 = 115605504
static constexpr size_t off_y1   = 123858176;               // bf16: 98*96*4608*2 = 86704128
// y2..y6 reuse the f2s region (dead after conv1)
static constexpr size_t off_y2   = off_f2s + 0;             // bf16 98*128*1152*2 = 28901376
static constexpr size_t off_y3   = off_f2s + 28901376;      // 28901376
static constexpr size_t off_y4   = off_f2s + 57802752;      // bf16 98*64*1152*2 = 14450688
static constexpr size_t off_y5   = off_f2s + 72253440;      // bf16 98*32*4608*2 = 28901376
static constexpr size_t off_y6   = off_f2s + 101154816;     // f32 98*4608*4 = 1806336
static constexpr size_t WS_NEEDED = 210562304;

// ---------------- small utility kernels ----------------
__global__ __launch_bounds__(256) void zero_k(float* __restrict__ p, int n) {
  int i = blockIdx.x * 256 + threadIdx.x;
  if (i < n) p[i] = 0.f;
}

__global__ __launch_bounds__(256) void cvt_bf16_k(const float* __restrict__ x, bf16* __restrict__ y, int n) {
  int i = blockIdx.x * 256 + threadIdx.x;
  if (i < n) y[i] = __float2bfloat16(x[i]);
}

// w[Cout][CinTot][3][3] -> wT[ci][k][oc]   (ci in [ciOff, ciOff+CinSub))
__global__ __launch_bounds__(256) void wtrans_k(const float* __restrict__ w, float* __restrict__ wT,
                                                int Cout, int CinTot, int ciOff, int CinSub) {
  int idx = blockIdx.x * 256 + threadIdx.x;
  int total = CinSub * 9 * Cout;
  if (idx >= total) return;
  int oc = idx % Cout;
  int k  = (idx / Cout) % 9;
  int ci = idx / (9 * Cout);
  wT[idx] = w[((size_t)oc * CinTot + ciOff + ci) * 9 + k];
}

// w5[I=64][O=32][4][4] -> wT[ph][pw][ci][th][tw][oc];  kh = 3-ph-2*th, kw = 3-pw-2*tw
__global__ __launch_bounds__(256) void w5trans_k(const float* __restrict__ w5, float* __restrict__ wT) {
  int idx = blockIdx.x * 256 + threadIdx.x; // 32768 total
  if (idx >= 32768) return;
  int oc = idx & 31;
  int tw = (idx >> 5) & 1;
  int th = (idx >> 6) & 1;
  int ci = (idx >> 7) & 63;
  int pw = (idx >> 13) & 1;
  int ph = (idx >> 14) & 1;
  int kh = 3 - ph - 2 * th, kw = 3 - pw - 2 * tw;
  wT[idx] = w5[(((size_t)ci * 32 + oc) * 4 + kh) * 4 + kw];
}

// ---------------- correlation sampling: f2s[n][c][h][w] (bf16) ----------------
__global__ __launch_bounds__(256) void sample_k(const float* __restrict__ f2, const float* __restrict__ coords,
                                                bf16* __restrict__ f2s) {
  long long o = (long long)blockIdx.x * 256 + threadIdx.x;
  const long long total = (long long)Nn * Cc * HW;
  if (o >= total) return;
  int w = (int)(o % Ww);
  int h = (int)((o / Ww) % Hh);
  int c = (int)((o / HW) % Cc);
  int n = (int)(o / ((long long)HW * Cc));
  int b = n / DD, d = n % DD;
  float sx = (float)(d / 7 - 3), sy = (float)(d % 7 - 3);
  int hw = h * Ww + w;
  float gx = coords[(size_t)b * 2 * HW + hw] + sx;
  float gy = coords[((size_t)b * 2 + 1) * HW + hw] + sy;
  float x0f = floorf(gx), y0f = floorf(gy);
  float wx = gx - x0f, wy = gy - y0f;
  int x0 = (int)x0f, y0 = (int)y0f;
  const float* img = f2 + ((size_t)b * Cc + c) * HW;
  float s = 0.f;
  if (x0 >= 0   && x0 < Ww   && y0 >= 0   && y0 < Hh)   s += (1.f - wx) * (1.f - wy) * img[y0 * Ww + x0];
  if (x0+1 >= 0 && x0+1 < Ww && y0 >= 0   && y0 < Hh)   s += wx * (1.f - wy) * img[y0 * Ww + x0 + 1];
  if (x0 >= 0   && x0 < Ww   && y0+1 >= 0 && y0+1 < Hh) s += (1.f - wx) * wy * img[(y0 + 1) * Ww + x0];
  if (x0+1 >= 0 && x0+1 < Ww && y0+1 >= 0 && y0+1 < Hh) s += wx * wy * img[(y0 + 1) * Ww + x0 + 1];
  f2s[o] = __float2bfloat16(s);
}

// ---------------- generic direct 3x3 conv, pad=1 ----------------
// Tile: TH output rows x full output width (TW = TWG*WPT == Wout). Each thread: WPT
// consecutive ow, OCC output channels. Input channel staged per-ci into LDS (f32).
// Weights wT[ci][k][oc] read with wave-uniform indices -> scalar loads.
template<int STRIDE, int OCC, int TH, int TWG, int WPT, bool OUT_F32, bool HAS_BASE, bool HAS_BIAS>
__global__ __launch_bounds__(TH * TWG)
void conv3x3_k(const bf16* __restrict__ in, const float* __restrict__ wT,
               void* __restrict__ outv, const float* __restrict__ base,
               const float* __restrict__ bias,
               int N, int Cin, int Hin, int Win, int Cout, int Hout, int Wout,
               int tilesH) {
  constexpr int TW = TWG * WPT;
  constexpr int PH = (TH - 1) * STRIDE + 3;
  constexpr int PW = (TW - 1) * STRIDE + 3;
  constexpr int NT = TH * TWG;
  constexpr int NV = (WPT - 1) * STRIDE + 3;
  __shared__ float patch[PH * PW];

  int nOc = Cout / OCC;
  int bid = blockIdx.x;
  int ocb = bid % nOc;
  int t   = bid / nOc;
  int ht  = t % tilesH;
  int n   = t / tilesH;
  int oc0 = ocb * OCC;
  int tid = threadIdx.x;
  int g   = tid % TWG;
  int ty  = tid / TWG;
  int oh  = ht * TH + ty;
  int ow0 = g * WPT;
  int ih0 = ht * TH * STRIDE - 1;

  float acc[OCC][WPT];
#pragma unroll
  for (int a = 0; a < OCC; ++a)
#pragma unroll
    for (int p = 0; p < WPT; ++p) acc[a][p] = 0.f;

  const bf16* inN = in + (size_t)n * Cin * Hin * Win;

  for (int ci = 0; ci < Cin; ++ci) {
    __syncthreads();
    const bf16* plane = inN + (size_t)ci * Hin * Win;
    for (int idx = tid; idx < PH * PW; idx += NT) {
      int py = idx / PW, px = idx % PW;
      int ih = ih0 + py, iw = px - 1;
      float v = 0.f;
      if (ih >= 0 && ih < Hin && iw >= 0 && iw < Win) v = __bfloat162float(plane[ih * Win + iw]);
      patch[idx] = v;
    }
    __syncthreads();

    float v[3][NV];
#pragma unroll
    for (int r = 0; r < 3; ++r)
#pragma unroll
      for (int c = 0; c < NV; ++c)
        v[r][c] = patch[(ty * STRIDE + r) * PW + ow0 * STRIDE + c];

    const float* wci = wT + (size_t)ci * 9 * Cout + oc0;   // uniform -> s_load
#pragma unroll
    for (int oc = 0; oc < OCC; ++oc) {
#pragma unroll
      for (int k = 0; k < 9; ++k) {
        float wv = wci[k * Cout + oc];
        int kh = k / 3, kw = k % 3;
#pragma unroll
        for (int p = 0; p < WPT; ++p)
          acc[oc][p] += wv * v[kh][p * STRIDE + kw];
      }
    }
  }

  size_t ohw   = (size_t)oh * Wout + ow0;
  size_t obase = ((size_t)n * Cout + oc0) * Hout * Wout + ohw;
  const float* bb = nullptr;
  if (HAS_BASE) bb = base + ((size_t)(n / DD) * Cout + oc0) * Hout * Wout + ohw;
#pragma unroll
  for (int oc = 0; oc < OCC; ++oc) {
#pragma unroll
    for (int p = 0; p < WPT; ++p) {
      float val = acc[oc][p];
      if (HAS_BASE) val += bb[(size_t)oc * Hout * Wout + p];
      if (HAS_BIAS) val += bias[oc0 + oc];
      if (OUT_F32) ((float*)outv)[obase + (size_t)oc * Hout * Wout + p] = val;
      else         ((bf16*)outv)[obase + (size_t)oc * Hout * Wout + p] = __float2bfloat16(val);
    }
  }
}

// ---------------- ConvTranspose2d k=4 s=2 p=1 (64->32) ----------------
// Each thread computes a 2x2 output quad (all four parities -> wave-uniform weights).
template<int OCC>
__global__ __launch_bounds__(384)
void deconv_k(const bf16* __restrict__ in, const float* __restrict__ wT,
              bf16* __restrict__ out, int N, int Cin, int Hin, int Win, int Cout) {
  int nOc = Cout / OCC;
  int bid = blockIdx.x;
  int ocb = bid % nOc;
  int t   = bid / nOc;
  int qs  = t % 3;            // 3 slices of 8 quad-rows
  int n   = t / 3;
  int oc0 = ocb * OCC;
  int tid = threadIdx.x;      // 384 = 8*48
  int qw  = tid % 48;
  int qh  = qs * 8 + tid / 48;

  float acc[OCC][2][2];
#pragma unroll
  for (int a = 0; a < OCC; ++a)
#pragma unroll
    for (int i = 0; i < 2; ++i)
#pragma unroll
      for (int j = 0; j < 2; ++j) acc[a][i][j] = 0.f;

  const bf16* inN = in + (size_t)n * Cin * Hin * Win;
  for (int ci = 0; ci < Cin; ++ci) {
    const bf16* plane = inN + (size_t)ci * Hin * Win;
    float v[3][3];
#pragma unroll
    for (int r = 0; r < 3; ++r)
#pragma unroll
      for (int c = 0; c < 3; ++c) {
        int ih = qh - 1 + r, iw = qw - 1 + c;
        v[r][c] = (ih >= 0 && ih < Hin && iw >= 0 && iw < Win) ? __bfloat162float(plane[ih * Win + iw]) : 0.f;
      }
#pragma unroll
    for (int ph = 0; ph < 2; ++ph)
#pragma unroll
      for (int pw = 0; pw < 2; ++pw)
#pragma unroll
        for (int th = 0; th < 2; ++th)
#pragma unroll
          for (int tw = 0; tw < 2; ++tw) {
            float iv = v[th + ph][tw + pw];
            const float* wp = wT + ((((size_t)(ph * 2 + pw) * Cin + ci) * 2 + th) * 2 + tw) * Cout + oc0;
#pragma unroll
            for (int oc = 0; oc < OCC; ++oc) acc[oc][ph][pw] += wp[oc] * iv;
          }
  }
  int HWo = 4 * Hin * Win;
#pragma unroll
  for (int oc = 0; oc < OCC; ++oc)
#pragma unroll
    for (int ph = 0; ph < 2; ++ph)
#pragma unroll
      for (int pw = 0; pw < 2; ++pw)
        out[((size_t)n * Cout + oc0 + oc) * HWo + (size_t)(2 * qh + ph) * (2 * Win) + 2 * qw + pw] =
            __float2bfloat16(acc[oc][ph][pw]);
}

// ---------------- BN stats (sum, sumsq per channel) ----------------
__global__ __launch_bounds__(256)
void stats_k(const bf16* __restrict__ y, float* __restrict__ sums, int C, int plane, int N, int nPer) {
  int c  = blockIdx.x % C;
  int ng = blockIdx.x / C;
  int n0 = ng * nPer;
  int n1 = n0 + nPer; if (n1 > N) n1 = N;
  float s = 0.f, ss = 0.f;
  for (int n = n0; n < n1; ++n) {
    const bf16* p = y + ((size_t)n * C + c) * plane;
    for (int i = threadIdx.x; i < plane; i += 256) {
      float v = __bfloat162float(p[i]);
      s += v; ss += v * v;
    }
  }
#pragma unroll
  for (int off = 32; off > 0; off >>= 1) { s += __shfl_down(s, off); ss += __shfl_down(ss, off); }
  __shared__ float rs[4], rss[4];
  int wv = threadIdx.x >> 6;
  if ((threadIdx.x & 63) == 0) { rs[wv] = s; rss[wv] = ss; }
  __syncthreads();
  if (threadIdx.x == 0) {
    float S = rs[0] + rs[1] + rs[2] + rs[3], SS = rss[0] + rss[1] + rss[2] + rss[3];
    atomicAdd(&sums[c], S);
    atomicAdd(&sums[C + c], SS);
  }
}

__global__ void bnfin_k(const float* __restrict__ sums, const float* __restrict__ gamma,
                        const float* __restrict__ beta, float* __restrict__ ab, int C, float invCnt) {
  int c = blockIdx.x * blockDim.x + threadIdx.x;
  if (c >= C) return;
  float mean = sums[c] * invCnt;
  float var  = sums[C + c] * invCnt - mean * mean;
  float a = gamma[c] * rsqrtf(var + 1e-5f);
  ab[c] = a;
  ab[C + c] = beta[c] - mean * a;
}

// in-place y = relu(a*y + b), bf16, vectorized by 4
__global__ __launch_bounds__(256)
void bnrelu_k(bf16* __restrict__ y, const float* __restrict__ ab, int C, int plane4, int total4) {
  for (int i = blockIdx.x * 256 + threadIdx.x; i < total4; i += gridDim.x * 256) {
    int c = (i / plane4) % C;
    float a = ab[c], b = ab[C + c];
    union { uint2 u; bf16 h[4]; } iv, ov;
    iv.u = *reinterpret_cast<const uint2*>(y + (size_t)i * 4);
#pragma unroll
    for (int j = 0; j < 4; ++j) {
      float f = fmaxf(a * __bfloat162float(iv.h[j]) + b, 0.f);
      ov.h[j] = __float2bfloat16(f);
    }
    *reinterpret_cast<uint2*>(y + (size_t)i * 4) = ov.u;
  }
}

// ---------------- DAP: out[b][e][hw] = sum_d dap[e][d] * y6[b*49+d][hw] ----------------
__global__ __launch_bounds__(256)
void dap_k(const float* __restrict__ y6, const float* __restrict__ dap, float* __restrict__ out) {
  int o = blockIdx.x * 256 + threadIdx.x;
  if (o >= Bb * DD * HW) return;
  int hw = o % HW;
  int e  = (o / HW) % DD;
  int b  = o / (HW * DD);
  float s = 0.f;
#pragma unroll 7
  for (int d = 0; d < DD; ++d) s += dap[e * DD + d] * y6[((size_t)(b * DD + d)) * HW + hw];
  out[o] = s;
}

// ---------------- host launch ----------------
extern "C" void kernel_launch(void* const* d_in, const int* in_sizes, int n_in,
                              void* d_out, int out_size, void* d_ws, size_t ws_size,
                              hipStream_t stream) {
  const float* f1     = (const float*)d_in[0];
  const float* f2     = (const float*)d_in[1];
  const float* coords = (const float*)d_in[2];
  const float* w1 = (const float*)d_in[3];
  const float* g1 = (const float*)d_in[4];
  const float* b1 = (const float*)d_in[5];
  const float* w2 = (const float*)d_in[6];
  const float* g2 = (const float*)d_in[7];
  const float* b2 = (const float*)d_in[8];
  const float* w3 = (const float*)d_in[9];
  const float* g3 = (const float*)d_in[10];
  const float* b3 = (const float*)d_in[11];
  const float* w4 = (const float*)d_in[12];
  const float* g4 = (const float*)d_in[13];
  const float* b4 = (const float*)d_in[14];
  const float* w5 = (const float*)d_in[15];
  const float* g5 = (const float*)d_in[16];
  const float* b5 = (const float*)d_in[17];
  const float* w6 = (const float*)d_in[18];
  const float* b6 = (const float*)d_in[19];
  const float* dap = (const float*)d_in[20];
  float* out = (float*)d_out;
  char* ws = (char*)d_ws;
  if (ws_size < WS_NEEDED) return;  // insufficient scratch; fail cleanly

  float* wT1a = (float*)(ws + off_wT1a);
  float* wT1b = (float*)(ws + off_wT1b);
  float* wT2  = (float*)(ws + off_wT2);
  float* wT3  = (float*)(ws + off_wT3);
  float* wT4  = (float*)(ws + off_wT4);
  float* wT5  = (float*)(ws + off_wT5);
  float* wT6  = (float*)(ws + off_wT6);
  bf16*  f1b  = (bf16*)(ws + off_f1b);
  float* y1a  = (float*)(ws + off_y1a);
  bf16*  f2s  = (bf16*)(ws + off_f2s);
  bf16*  y1   = (bf16*)(ws + off_y1);
  bf16*  y2   = (bf16*)(ws + off_y2);
  bf16*  y3   = (bf16*)(ws + off_y3);
  bf16*  y4   = (bf16*)(ws + off_y4);
  bf16*  y5   = (bf16*)(ws + off_y5);
  float* y6   = (float*)(ws + off_y6);
  float* st0  = (float*)(ws + off_stats + 0 * 2048);
  float* st1  = (float*)(ws + off_stats + 1 * 2048);
  float* st2  = (float*)(ws + off_stats + 2 * 2048);
  float* st3  = (float*)(ws + off_stats + 3 * 2048);
  float* st4  = (float*)(ws + off_stats + 4 * 2048);

  // 0) zero the atomic-accumulated stats region (2560 floats)
  zero_k<<<10, 256, 0, stream>>>((float*)(ws + off_stats), 2560);

  // 1) weight transposes
  wtrans_k<<<432, 256, 0, stream>>>(w1, wT1a, 96, 256, 0, 128);
  wtrans_k<<<432, 256, 0, stream>>>(w1, wT1b, 96, 256, 128, 128);
  wtrans_k<<<432, 256, 0, stream>>>(w2, wT2, 128, 96, 0, 96);
  wtrans_k<<<576, 256, 0, stream>>>(w3, wT3, 128, 128, 0, 128);
  wtrans_k<<<288, 256, 0, stream>>>(w4, wT4, 64, 128, 0, 128);
  wtrans_k<<<2,   256, 0, stream>>>(w6, wT6, 1, 32, 0, 32);
  w5trans_k<<<128, 256, 0, stream>>>(w5, wT5);

  // 2) f1 -> bf16
  cvt_bf16_k<<<4608, 256, 0, stream>>>(f1, f1b, Bb * Cc * HW);

  // 3) correlation sampling -> f2s (bf16)
  sample_k<<<225792, 256, 0, stream>>>(f2, coords, f2s);

  // 4) y1a = conv3x3(f1, w1[:, :128])  (f32, shared across 49 displacements)
  conv3x3_k<1, 4, 16, 16, 6, true, false, false><<<144, 256, 0, stream>>>(
      f1b, wT1a, y1a, nullptr, nullptr, Bb, 128, Hh, Ww, 96, Hh, Ww, 3);

  // 5) y1 = y1a[b] + conv3x3(f2s, w1[:, 128:])  (bf16)
  conv3x3_k<1, 16, 16, 16, 6, false, true, false><<<1764, 256, 0, stream>>>(
      f2s, wT1b, y1, y1a, nullptr, Nn, 128, Hh, Ww, 96, Hh, Ww, 3);

  // 6) BN1 + ReLU (in place)
  stats_k<<<96 * 7, 256, 0, stream>>>(y1, st0, 96, HW, Nn, 14);
  bnfin_k<<<1, 256, 0, stream>>>(st0, g1, b1, st0 + 256, 96, 1.f / (98.f * 4608.f));
  bnrelu_k<<<2048, 256, 0, stream>>>(y1, st0 + 256, 96, HW / 4, Nn * 96 * HW / 4);

  // 7) conv2 (stride 2) + BN2 + ReLU
  conv3x3_k<2, 16, 24, 16, 3, false, false, false><<<784, 384, 0, stream>>>(
      y1, wT2, y2, nullptr, nullptr, Nn, 96, Hh, Ww, 128, H2, W2, 1);
  stats_k<<<128 * 7, 256, 0, stream>>>(y2, st1, 128, HW2, Nn, 14);
  bnfin_k<<<1, 256, 0, stream>>>(st1, g2, b2, st1 + 256, 128, 1.f / (98.f * 1152.f));
  bnrelu_k<<<2048, 256, 0, stream>>>(y2, st1 + 256, 128, HW2 / 4, Nn * 128 * HW2 / 4);

  // 8) conv3 + BN3 + ReLU
  conv3x3_k<1, 16, 24, 16, 3, false, false, false><<<784, 384, 0, stream>>>(
      y2, wT3, y3, nullptr, nullptr, Nn, 128, H2, W2, 128, H2, W2, 1);
  stats_k<<<128 * 7, 256, 0, stream>>>(y3, st2, 128, HW2, Nn, 14);
  bnfin_k<<<1, 256, 0, stream>>>(st2, g3, b3, st2 + 256, 128, 1.f / (98.f * 1152.f));
  bnrelu_k<<<2048, 256, 0, stream>>>(y3, st2 + 256, 128, HW2 / 4, Nn * 128 * HW2 / 4);

  // 9) conv4 + BN4 + ReLU
  conv3x3_k<1, 16, 24, 16, 3, false, false, false><<<392, 384, 0, stream>>>(
      y3, wT4, y4, nullptr, nullptr, Nn, 128, H2, W2, 64, H2, W2, 1);
  stats_k<<<64 * 7, 256, 0, stream>>>(y4, st3, 64, HW2, Nn, 14);
  bnfin_k<<<1, 256, 0, stream>>>(st3, g4, b4, st3 + 256, 64, 1.f / (98.f * 1152.f));
  bnrelu_k<<<2048, 256, 0, stream>>>(y4, st3 + 256, 64, HW2 / 4, Nn * 64 * HW2 / 4);

  // 10) deconv + BN5 + ReLU
  deconv_k<16><<<588, 384, 0, stream>>>(y4, wT5, y5, Nn, 64, H2, W2, 32);
  stats_k<<<32 * 7, 256, 0, stream>>>(y5, st4, 32, HW, Nn, 14);
  bnfin_k<<<1, 256, 0, stream>>>(st4, g5, b5, st4 + 256, 32, 1.f / (98.f * 4608.f));
  bnrelu_k<<<2048, 256, 0, stream>>>(y5, st4 + 256, 32, HW / 4, Nn * 32 * HW / 4);

  // 11) conv6 (+bias, f32 out)
  conv3x3_k<1, 1, 16, 16, 6, true, false, true><<<294, 256, 0, stream>>>(
      y5, wT6, y6, nullptr, b6, Nn, 32, Hh, Ww, 1, Hh, Ww, 3);

  // 12) DAP -> d_out
  dap_k<<<1764, 256, 0, stream>>>(y6, dap, out);
}

// Round 2
// 1219.203 us; speedup vs baseline: 4.6963x; 4.6963x over previous
//
#include <hip/hip_runtime.h>
#include <hip/hip_bf16.h>

using bf16 = __hip_bfloat16;
typedef __attribute__((ext_vector_type(8))) short s8v;
typedef __attribute__((ext_vector_type(4))) float f4v;
typedef __attribute__((ext_vector_type(16))) float f16v;

static constexpr int Bb = 2, Hh = 48, Ww = 96;
static constexpr int HW = Hh * Ww;              // 4608
static constexpr int DD = 49, Nn = Bb * DD;     // 98
static constexpr int H2 = 24, W2 = 48, HW2 = H2 * W2;

// ---------------- workspace layout (bytes) ----------------
static constexpr size_t off_wf1a = 0;                 // 221184
static constexpr size_t off_wf1b = 221184;            // 221184
static constexpr size_t off_wf3  = 442368;            // 294912
static constexpr size_t off_wf2  = 737280;            // 221184
static constexpr size_t off_wf4  = 958464;            // 147456
static constexpr size_t off_wf5  = 1105920;           // 65536
static constexpr size_t off_f1t  = 1171456;           // bf16 [2][4608][128] = 2359296
static constexpr size_t off_y1a  = 3530752;           // f32  [2][4608][96]  = 3538944
static constexpr size_t off_stats= 7069696;           // 5*2048
static constexpr size_t off_f2s  = 7079936;           // bf16 [98][4608][128] = 115605504
static constexpr size_t off_y1   = 122685440;         // bf16 [98][4608][96] = 86704128
static constexpr size_t off_f2t  = off_y1;            // f32 [2][4608][128] = 4718592 (dead before y1 written)
static constexpr size_t off_y2   = off_f2s;                   // bf16 [98][1152][128]
static constexpr size_t off_y3   = off_f2s + 28901376;        // bf16 [98][1152][128]
static constexpr size_t off_y4   = off_f2s + 57802752;        // bf16 [98][1152][64]
static constexpr size_t off_y5   = off_f2s + 72253440;        // bf16 [98][4608][32]
static constexpr size_t off_y6   = off_f2s + 101154816;       // f32 [98][4608]
static constexpr size_t WS_NEEDED = 209389568;

// ---------------- helpers ----------------
__device__ __forceinline__ float bf2f(unsigned short h) {
  return __uint_as_float(((unsigned)h) << 16);
}
__device__ __forceinline__ unsigned short f2bf(float f) {
  __hip_bfloat16 h = __float2bfloat16(f);
  union { __hip_bfloat16 x; unsigned short u; } cv; cv.x = h; return cv.u;
}
template<bool EN>
__device__ __forceinline__ uint4 bn8(uint4 v, const float* a, const float* b, int c0) {
  if constexpr (!EN) return v;
  union { uint4 u; unsigned short h[8]; } X; X.u = v;
#pragma unroll
  for (int i = 0; i < 8; ++i) {
    float f = fmaxf(bf2f(X.h[i]) * a[c0 + i] + b[c0 + i], 0.f);
    X.h[i] = f2bf(f);
  }
  return X.u;
}

// ---------------- small utility kernels ----------------
__global__ __launch_bounds__(256) void zero_k(float* __restrict__ p, int n) {
  int i = blockIdx.x * 256 + threadIdx.x;
  if (i < n) p[i] = 0.f;
}

// f2 [2][128][4608] f32 -> f2t [2][4608][128] f32
__global__ __launch_bounds__(256) void tr_f2_k(const float* __restrict__ f2, float* __restrict__ f2t) {
  int o = blockIdx.x * 256 + threadIdx.x;
  if (o >= 2 * HW * 16) return;
  int c8 = o & 15; int pos = (o >> 4) % HW; int b = o / (HW * 16);
  float v[8];
#pragma unroll
  for (int i = 0; i < 8; ++i) v[i] = f2[((size_t)(b * 128 + c8 * 8 + i)) * HW + pos];
  float* dst = f2t + ((size_t)b * HW + pos) * 128 + c8 * 8;
#pragma unroll
  for (int i = 0; i < 8; ++i) dst[i] = v[i];
}

// f1 [2][128][4608] f32 -> f1t [2][4608][128] bf16
__global__ __launch_bounds__(256) void tr_f1_k(const float* __restrict__ f1, bf16* __restrict__ f1t) {
  int o = blockIdx.x * 256 + threadIdx.x;
  if (o >= 2 * HW * 16) return;
  int c8 = o & 15; int pos = (o >> 4) % HW; int b = o / (HW * 16);
  union { uint4 u; unsigned short h[8]; } Y;
#pragma unroll
  for (int i = 0; i < 8; ++i) Y.h[i] = f2bf(f1[((size_t)(b * 128 + c8 * 8 + i)) * HW + pos]);
  *(uint4*)(f1t + ((size_t)b * HW + pos) * 128 + c8 * 8) = Y.u;
}

// weight prep: frag-ordered for 32x32x16 path.  [khw][cih][ks][nt][lh][ocl]x8bf16
__global__ __launch_bounds__(256)
void prep32_k(const float* __restrict__ w, uint4* __restrict__ wf, int NT, int CINT, int ciOff) {
  int idx = blockIdx.x * 256 + threadIdx.x;
  int total = 9 * 2 * 4 * NT * 64;
  if (idx >= total) return;
  int ocl = idx & 31; int lh = (idx >> 5) & 1;
  int q = idx >> 6; int nt = q % NT; int rest = q / NT;
  int ks = rest & 3; int cih = (rest >> 2) & 1; int khw = rest >> 3;
  int oc = nt * 32 + ocl;
  union { uint4 u; unsigned short h[8]; } Y;
#pragma unroll
  for (int i = 0; i < 8; ++i) {
    int ci = ciOff + cih * 64 + ks * 16 + lh * 8 + i;
    Y.h[i] = f2bf(w[((size_t)oc * CINT + ci) * 9 + khw]);
  }
  wf[idx] = Y.u;
}

// frag-ordered for 16x16x32 path.  [khw][st][ks][nt][lg][ocl]x8bf16
__global__ __launch_bounds__(256)
void prep16_k(const float* __restrict__ w, uint4* __restrict__ wf, int NT, int CINT,
              int NSTAGE, int CPS, int KPS) {
  int idx = blockIdx.x * 256 + threadIdx.x;
  int total = 9 * NSTAGE * KPS * NT * 64;
  if (idx >= total) return;
  int ocl = idx & 15; int lg = (idx >> 4) & 3;
  int q = idx >> 6; int nt = q % NT; int q2 = q / NT;
  int ks = q2 % KPS; int q3 = q2 / KPS;
  int st = q3 % NSTAGE; int khw = q3 / NSTAGE;
  int oc = nt * 16 + ocl;
  union { uint4 u; unsigned short h[8]; } Y;
#pragma unroll
  for (int i = 0; i < 8; ++i) {
    int ci = st * CPS + ks * 32 + lg * 8 + i;
    Y.h[i] = f2bf(w[((size_t)oc * CINT + ci) * 9 + khw]);
  }
  wf[idx] = Y.u;
}

// w5 [64ci][32oc][4][4] -> frag-ordered [p][ks][nt][lg][ocl]x8
__global__ __launch_bounds__(256)
void prep_w5_k(const float* __restrict__ w5, uint4* __restrict__ wf) {
  int idx = blockIdx.x * 256 + threadIdx.x;
  if (idx >= 4096) return;
  int ocl = idx & 15; int lg = (idx >> 4) & 3;
  int nt = (idx >> 6) & 1; int ks = (idx >> 7) & 7; int p = idx >> 10;
  int ph = p >> 1, pw = p & 1;
  int t = ks >> 2, u = (ks >> 1) & 1;
  int kh = 3 - ph - 2 * t, kw = 3 - pw - 2 * u;
  int oc = nt * 16 + ocl;
  union { uint4 u4; unsigned short h[8]; } Y;
#pragma unroll
  for (int i = 0; i < 8; ++i) {
    int ci = (ks & 1) * 32 + lg * 8 + i;
    Y.h[i] = f2bf(w5[(((size_t)ci * 32 + oc) * 4 + kh) * 4 + kw]);
  }
  wf[idx] = Y.u4;
}

// ---------------- correlation sampling -> f2s NHWC bf16 ----------------
__global__ __launch_bounds__(256)
void sample_k(const float* __restrict__ f2t, const float* __restrict__ coords,
              bf16* __restrict__ f2s) {
  int wv = blockIdx.x * 4 + (threadIdx.x >> 6);
  int lane = threadIdx.x & 63;
  int p0 = wv * 32;
  for (int k = 0; k < 32; ++k) {
    int P = p0 + k;
    int hw = P % HW; int n = P / HW;
    int b = n / DD, d = n % DD;
    float gx = coords[(size_t)b * 2 * HW + hw] + (float)(d / 7 - 3);
    float gy = coords[((size_t)b * 2 + 1) * HW + hw] + (float)(d % 7 - 3);
    float x0f = floorf(gx), y0f = floorf(gy);
    float wx = gx - x0f, wy = gy - y0f;
    int x0 = (int)x0f, y0 = (int)y0f;
    const float* base = f2t + (size_t)b * HW * 128;
    float r0 = 0.f, r1 = 0.f;
#pragma unroll
    for (int c = 0; c < 4; ++c) {
      int xi = x0 + (c & 1), yi = y0 + (c >> 1);
      float wgt = ((c & 1) ? wx : 1.f - wx) * ((c >> 1) ? wy : 1.f - wy);
      if (xi < 0 || xi >= Ww || yi < 0 || yi >= Hh) wgt = 0.f;
      int xc = min(max(xi, 0), Ww - 1), yc = min(max(yi, 0), Hh - 1);
      const float* pv = base + ((size_t)(yc * Ww + xc)) * 128 + 2 * lane;
      r0 += wgt * pv[0];
      r1 += wgt * pv[1];
    }
    unsigned pack = (unsigned)f2bf(r0) | ((unsigned)f2bf(r1) << 16);
    ((unsigned*)f2s)[(size_t)P * 64 + lane] = pack;
  }
}

// ---------------- 32x32x16 MFMA conv (stride 1, CIN=128) ----------------
template<int COUT, int NT, int MT, int NB, int GR, int GC, bool OUTF32, bool HAS_BASE, bool HAS_BN>
__global__ __launch_bounds__(((GR * GC) / MT) * (NT / NB) * 64)
void conv32_k(const bf16* __restrict__ in, const uint4* __restrict__ wf,
              void* __restrict__ outv, const float* __restrict__ base,
              const float* __restrict__ bn_a, const float* __restrict__ bn_b,
              int N, int H, int W, int DIV) {
  constexpr int NW = ((GR * GC) / MT) * (NT / NB);
  constexpr int BR = GR * 2, BC = GC * 16;
  constexpr int IR = BR + 2, IC = BC + 2;
  constexpr int INB = IR * IC * 128;
  constexpr int WCH = NT * 256;          // 16B chunks per (khw,cih) slice
  __shared__ __align__(16) char lds[INB + WCH * 16];

  const int tid = threadIdx.x;
  const int lane = tid & 63;
  const int wv = tid >> 6;
  const int lm = lane & 31, lh = lane >> 5;
  const int dh = lm >> 4, dw = lm & 15;
  constexpr int NG = NT / NB;
  const int mg = wv / NG, ng = wv % NG;

  const int tW = W / BC, tH = H / BR;
  const int tile = blockIdx.x % (tH * tW);
  const int n = blockIdx.x / (tH * tW);
  const int oh0 = (tile / tW) * BR, ow0 = (tile % tW) * BC;
  const size_t inbase = (size_t)n * H * W * 128;

  int trA[MT], tcA[MT];
#pragma unroll
  for (int i = 0; i < MT; ++i) { int mt = mg * MT + i; trA[i] = mt / GC; tcA[i] = mt % GC; }
  const int bb0 = INB + lh * 512 + lm * 16;

  f16v acc[MT][NB];
#pragma unroll
  for (int i = 0; i < MT; ++i)
#pragma unroll
    for (int j = 0; j < NB; ++j)
#pragma unroll
      for (int r = 0; r < 16; ++r) acc[i][j][r] = 0.f;

  for (int cih = 0; cih < 2; ++cih) {
    for (int khw = 0; khw < 9; ++khw) {
      __syncthreads();
      if (khw == 0) {
        for (int idx = tid; idx < IR * IC * 8; idx += NW * 64) {
          int h8 = idx & 7;
          int icl = (idx >> 3) % IC;
          int ihl = (idx >> 3) / IC;
          int ih = oh0 - 1 + ihl, iw = ow0 - 1 + icl;
          uint4 v = make_uint4(0u, 0u, 0u, 0u);
          if (ih >= 0 && ih < H && iw >= 0 && iw < W) {
            v = *(const uint4*)(in + inbase + ((size_t)(ih * W + iw)) * 128 + cih * 64 + h8 * 8);
            v = bn8<HAS_BN>(v, bn_a, bn_b, cih * 64 + h8 * 8);
          }
          int bbyte = (ihl * IC + icl) * 128 + h8 * 16;
          bbyte ^= (icl & 7) << 4;
          *(uint4*)(lds + bbyte) = v;
        }
      }
      {
        const uint4* src = wf + (khw * 2 + cih) * WCH;
        for (int idx = tid; idx < WCH; idx += NW * 64)
          *(uint4*)(lds + INB + idx * 16) = src[idx];
      }
      __syncthreads();
      const int kh = khw / 3, kw = khw % 3;
#pragma unroll
      for (int ks = 0; ks < 4; ++ks) {
        s8v Af[MT], Bf[NB];
#pragma unroll
        for (int i = 0; i < MT; ++i) {
          int rl = trA[i] * 2 + dh + kh;
          int cl = tcA[i] * 16 + dw + kw;
          int bbyte = (rl * IC + cl) * 128 + ks * 32 + lh * 16;
          bbyte ^= (cl & 7) << 4;
          Af[i] = *(const s8v*)(lds + bbyte);
        }
#pragma unroll
        for (int j = 0; j < NB; ++j)
          Bf[j] = *(const s8v*)(lds + bb0 + (ks * NT + ng * NB + j) * 1024);
#pragma unroll
        for (int i = 0; i < MT; ++i)
#pragma unroll
          for (int j = 0; j < NB; ++j)
            acc[i][j] = __builtin_amdgcn_mfma_f32_32x32x16_bf16(Af[i], Bf[j], acc[i][j], 0, 0, 0);
      }
    }
  }

  const size_t obase = (size_t)n * H * W * COUT;
  const float* bptr = nullptr;
  if constexpr (HAS_BASE) bptr = base + (size_t)(n / DIV) * H * W * COUT;
#pragma unroll
  for (int i = 0; i < MT; ++i) {
#pragma unroll
    for (int j = 0; j < NB; ++j) {
      int oc = (ng * NB + j) * 32 + lm;
#pragma unroll
      for (int r = 0; r < 16; ++r) {
        int row = (r & 3) + 8 * (r >> 2) + 4 * lh;
        int oh = oh0 + trA[i] * 2 + (row >> 4);
        int ow = ow0 + tcA[i] * 16 + (row & 15);
        size_t pix = (size_t)(oh * W + ow);
        float v = acc[i][j][r];
        if constexpr (HAS_BASE) v += bptr[pix * COUT + oc];
        if constexpr (OUTF32) ((float*)outv)[obase + pix * COUT + oc] = v;
        else ((bf16*)outv)[obase + pix * COUT + oc] = __float2bfloat16(v);
      }
    }
  }
}

// ---------------- 16x16x32 MFMA conv (stride 1 or 2) ----------------
template<int COUT, int NT, int MT, int NB, int GR, int GC, int STRIDE,
         int CINT, int CPS, int NSTAGE, int KPS, bool HAS_BN>
__global__ __launch_bounds__(((GR * GC) / MT) * (NT / NB) * 64)
void conv16_k(const bf16* __restrict__ in, const uint4* __restrict__ wf,
              bf16* __restrict__ out, const float* __restrict__ bn_a,
              const float* __restrict__ bn_b,
              int N, int HO, int WO, int HI, int WI) {
  constexpr int NW = ((GR * GC) / MT) * (NT / NB);
  constexpr int BR = GR, BC = GC * 16;
  constexpr int IR = STRIDE * (BR - 1) + 3;
  constexpr int IC = STRIDE * (BC - 1) + 3 + (STRIDE == 2 ? 1 : 0);
  constexpr int ROWB = CPS * 2;
  constexpr int SLOTM = ROWB / 16 - 1;
  constexpr int INB = IR * IC * ROWB;
  constexpr int WCH = KPS * NT * 64;
  __shared__ __align__(16) char lds[INB + WCH * 16];

  const int tid = threadIdx.x;
  const int lane = tid & 63;
  const int wv = tid >> 6;
  const int lm = lane & 15, lg = lane >> 4;
  constexpr int NG = NT / NB;
  const int mg = wv / NG, ng = wv % NG;

  const int tW = WO / BC, tH = HO / BR;
  const int tile = blockIdx.x % (tH * tW);
  const int n = blockIdx.x / (tH * tW);
  const int oh0 = (tile / tW) * BR, ow0 = (tile % tW) * BC;
  const int ih0 = STRIDE * oh0 - 1, iw0 = STRIDE * ow0 - 1;
  const size_t inbase = (size_t)n * HI * WI * CINT;

  int trA[MT], tcA[MT];
#pragma unroll
  for (int i = 0; i < MT; ++i) { int mt = mg * MT + i; trA[i] = mt / GC; tcA[i] = mt % GC; }

  f4v acc[MT][NB];
#pragma unroll
  for (int i = 0; i < MT; ++i)
#pragma unroll
    for (int j = 0; j < NB; ++j)
#pragma unroll
      for (int r = 0; r < 4; ++r) acc[i][j][r] = 0.f;

  for (int st = 0; st < NSTAGE; ++st) {
    for (int khw = 0; khw < 9; ++khw) {
      __syncthreads();
      if (khw == 0) {
        for (int idx = tid; idx < IR * IC * (CPS / 8); idx += NW * 64) {
          int h8 = idx % (CPS / 8);
          int rest = idx / (CPS / 8);
          int icl = rest % IC;
          int ihl = rest / IC;
          int ih = ih0 + ihl, iw = iw0 + icl;
          uint4 v = make_uint4(0u, 0u, 0u, 0u);
          if (ih >= 0 && ih < HI && iw >= 0 && iw < WI) {
            v = *(const uint4*)(in + inbase + ((size_t)(ih * WI + iw)) * CINT + st * CPS + h8 * 8);
            v = bn8<HAS_BN>(v, bn_a, bn_b, st * CPS + h8 * 8);
          }
          int bbyte = (ihl * IC + icl) * ROWB + h8 * 16;
          bbyte ^= ((icl >> (STRIDE - 1)) & SLOTM) << 4;
          *(uint4*)(lds + bbyte) = v;
        }
      }
      {
        const uint4* src = wf + (khw * NSTAGE + st) * WCH;
        for (int idx = tid; idx < WCH; idx += NW * 64)
          *(uint4*)(lds + INB + idx * 16) = src[idx];
      }
      __syncthreads();
      const int kh = khw / 3, kw = khw % 3;
#pragma unroll
      for (int ks = 0; ks < KPS; ++ks) {
        s8v Af[MT], Bf[NB];
#pragma unroll
        for (int i = 0; i < MT; ++i) {
          int rl = STRIDE * trA[i] + kh;
          int cl = STRIDE * (tcA[i] * 16 + lm) + kw;
          int bbyte = (rl * IC + cl) * ROWB + ks * 64 + lg * 16;
          bbyte ^= ((cl >> (STRIDE - 1)) & SLOTM) << 4;
          Af[i] = *(const s8v*)(lds + bbyte);
        }
#pragma unroll
        for (int j = 0; j < NB; ++j)
          Bf[j] = *(const s8v*)(lds + INB + ((ks * NT + ng * NB + j) * 64 + lg * 16 + lm) * 16);
#pragma unroll
        for (int i = 0; i < MT; ++i)
#pragma unroll
          for (int j = 0; j < NB; ++j)
            acc[i][j] = __builtin_amdgcn_mfma_f32_16x16x32_bf16(Af[i], Bf[j], acc[i][j], 0, 0, 0);
      }
    }
  }

  const size_t obase = (size_t)n * HO * WO * COUT;
#pragma unroll
  for (int i = 0; i < MT; ++i) {
#pragma unroll
    for (int j = 0; j < NB; ++j) {
      int oc = (ng * NB + j) * 16 + lm;
#pragma unroll
      for (int r = 0; r < 4; ++r) {
        int oh = oh0 + trA[i];
        int ow = ow0 + tcA[i] * 16 + lg * 4 + r;
        out[obase + (size_t)(oh * WO + ow) * COUT + oc] = __float2bfloat16(acc[i][j][r]);
      }
    }
  }
}

// ---------------- deconv (ConvTranspose2d k4 s2 p1, 64->32) via 16x16x32 ----------------
__global__ __launch_bounds__(256)
void deconv16_k(const bf16* __restrict__ in, const uint4* __restrict__ wf5,
                bf16* __restrict__ out, const float* __restrict__ a4,
                const float* __restrict__ b4) {
  constexpr int IR = 6, IC = 50, INB = IR * IC * 128;
  __shared__ __align__(16) char lds[INB + 16384];
  const int tid = threadIdx.x;
  const int lane = tid & 63, wv = tid >> 6;
  const int lm = lane & 15, lg = lane >> 4;
  const int n = blockIdx.x / 6;
  const int qh0 = (blockIdx.x % 6) * 4;
  const size_t ibase = (size_t)n * HW2 * 64;

  for (int idx = tid; idx < IR * IC * 8; idx += 256) {
    int h8 = idx & 7; int icl = (idx >> 3) % IC; int ihl = (idx >> 3) / IC;
    int ih = qh0 - 1 + ihl, iw = -1 + icl;
    uint4 v = make_uint4(0u, 0u, 0u, 0u);
    if (ih >= 0 && ih < H2 && iw >= 0 && iw < W2) {
      v = *(const uint4*)(in + ibase + ((size_t)(ih * W2 + iw)) * 64 + h8 * 8);
      v = bn8<true>(v, a4, b4, h8 * 8);
    }
    int bbyte = (ihl * IC + icl) * 128 + h8 * 16;
    bbyte ^= (icl & 7) << 4;
    *(uint4*)(lds + bbyte) = v;
  }
  int trA[3], tcA[3];
#pragma unroll
  for (int i = 0; i < 3; ++i) { int mt = wv * 3 + i; trA[i] = mt / 3; tcA[i] = mt % 3; }

  for (int p = 0; p < 4; ++p) {
    __syncthreads();
    for (int idx = tid; idx < 1024; idx += 256)
      *(uint4*)(lds + INB + idx * 16) = wf5[p * 1024 + idx];
    __syncthreads();
    const int ph = p >> 1, pw = p & 1;
    f4v acc[3][2];
#pragma unroll
    for (int i = 0; i < 3; ++i)
#pragma unroll
      for (int j = 0; j < 2; ++j)
#pragma unroll
        for (int r = 0; r < 4; ++r) acc[i][j][r] = 0.f;
#pragma unroll
    for (int ks = 0; ks < 8; ++ks) {
      int t = ks >> 2, u = (ks >> 1) & 1, cb = ks & 1;
      s8v Af[3], Bf[2];
#pragma unroll
      for (int i = 0; i < 3; ++i) {
        int rl = trA[i] + t + ph;
        int cl = tcA[i] * 16 + lm + u + pw;
        int bbyte = (rl * IC + cl) * 128 + cb * 64 + lg * 16;
        bbyte ^= (cl & 7) << 4;
        Af[i] = *(const s8v*)(lds + bbyte);
      }
#pragma unroll
      for (int j = 0; j < 2; ++j)
        Bf[j] = *(const s8v*)(lds + INB + ((ks * 2 + j) * 64 + lg * 16 + lm) * 16);
#pragma unroll
      for (int i = 0; i < 3; ++i)
#pragma unroll
        for (int j = 0; j < 2; ++j)
          acc[i][j] = __builtin_amdgcn_mfma_f32_16x16x32_bf16(Af[i], Bf[j], acc[i][j], 0, 0, 0);
    }
#pragma unroll
    for (int i = 0; i < 3; ++i) {
#pragma unroll
      for (int j = 0; j < 2; ++j) {
        int oc = j * 16 + lm;
#pragma unroll
        for (int r = 0; r < 4; ++r) {
          int qh = qh0 + trA[i];
          int qw = tcA[i] * 16 + lg * 4 + r;
          int oh = 2 * qh + ph, ow = 2 * qw + pw;
          out[((size_t)n * HW + oh * Ww + ow) * 32 + oc] = __float2bfloat16(acc[i][j][r]);
        }
      }
    }
  }
}

// ---------------- BN stats (NHWC) ----------------
template<int C, int TPB>
__global__ __launch_bounds__(TPB)
void stats_k(const bf16* __restrict__ y, float* __restrict__ st, int NP) {
  constexpr int CP = C / 2;
  constexpr int RPB = TPB / CP;
  const int t = threadIdx.x;
  const int c2 = t % CP, rep = t / CP;
  float s0 = 0.f, s1 = 0.f, q0 = 0.f, q1 = 0.f;
  for (int p = blockIdx.x * RPB + rep; p < NP; p += gridDim.x * RPB) {
    unsigned v = *(const unsigned*)(y + (size_t)p * C + 2 * c2);
    float f0 = bf2f((unsigned short)(v & 0xffff)), f1 = bf2f((unsigned short)(v >> 16));
    s0 += f0; q0 += f0 * f0; s1 += f1; q1 += f1 * f1;
  }
  __shared__ float red[4][TPB];
  red[0][t] = s0; red[1][t] = q0; red[2][t] = s1; red[3][t] = q1;
  __syncthreads();
  if (t < CP) {
    float S0 = 0, Q0 = 0, S1 = 0, Q1 = 0;
    for (int r = 0; r < RPB; ++r) {
      S0 += red[0][r * CP + t]; Q0 += red[1][r * CP + t];
      S1 += red[2][r * CP + t]; Q1 += red[3][r * CP + t];
    }
    atomicAdd(&st[2 * t], S0);     atomicAdd(&st[C + 2 * t], Q0);
    atomicAdd(&st[2 * t + 1], S1); atomicAdd(&st[C + 2 * t + 1], Q1);
  }
}

__global__ void bnfin_k(const float* __restrict__ sums, const float* __restrict__ gamma,
                        const float* __restrict__ beta, float* __restrict__ ab, int C, float invCnt) {
  int c = blockIdx.x * blockDim.x + threadIdx.x;
  if (c >= C) return;
  float mean = sums[c] * invCnt;
  float var = sums[C + c] * invCnt - mean * mean;
  float a = gamma[c] * rsqrtf(var + 1e-5f);
  ab[c] = a;
  ab[C + c] = beta[c] - mean * a;
}

// ---------------- conv6 (32->1, 3x3, fused bn5) ----------------
__global__ __launch_bounds__(256)
void conv6_k(const bf16* __restrict__ y5, const float* __restrict__ w6,
             const float* __restrict__ b6, const float* __restrict__ a5,
             const float* __restrict__ bb5, float* __restrict__ y6) {
  int o = blockIdx.x * 256 + threadIdx.x;
  if (o >= Nn * HW) return;
  int hw = o % HW; int n = o / HW;
  int h = hw / Ww, w = hw % Ww;
  float acc = b6[0];
  for (int kh = 0; kh < 3; ++kh) {
    int ih = h - 1 + kh; if (ih < 0 || ih >= Hh) continue;
    for (int kw = 0; kw < 3; ++kw) {
      int iw = w - 1 + kw; if (iw < 0 || iw >= Ww) continue;
      const bf16* p = y5 + ((size_t)n * HW + ih * Ww + iw) * 32;
      int khw = kh * 3 + kw;
#pragma unroll
      for (int c8 = 0; c8 < 4; ++c8) {
        union { uint4 u; unsigned short hh[8]; } X;
        X.u = *(const uint4*)(p + c8 * 8);
#pragma unroll
        for (int i = 0; i < 8; ++i) {
          int c = c8 * 8 + i;
          float f = fmaxf(bf2f(X.hh[i]) * a5[c] + bb5[c], 0.f);
          acc += f * w6[c * 9 + khw];
        }
      }
    }
  }
  y6[o] = acc;
}

// ---------------- DAP ----------------
__global__ __launch_bounds__(256)
void dap_k(const float* __restrict__ y6, const float* __restrict__ dap, float* __restrict__ out) {
  int o = blockIdx.x * 256 + threadIdx.x;
  if (o >= Bb * DD * HW) return;
  int hw = o % HW;
  int e = (o / HW) % DD;
  int b = o / (HW * DD);
  float s = 0.f;
#pragma unroll 7
  for (int d = 0; d < DD; ++d) s += dap[e * DD + d] * y6[((size_t)(b * DD + d)) * HW + hw];
  out[o] = s;
}

// ---------------- host launch ----------------
extern "C" void kernel_launch(void* const* d_in, const int* in_sizes, int n_in,
                              void* d_out, int out_size, void* d_ws, size_t ws_size,
                              hipStream_t stream) {
  const float* f1 = (const float*)d_in[0];
  const float* f2 = (const float*)d_in[1];
  const float* coords = (const float*)d_in[2];
  const float* w1 = (const float*)d_in[3];
  const float* g1 = (const float*)d_in[4];
  const float* b1 = (const float*)d_in[5];
  const float* w2 = (const float*)d_in[6];
  const float* g2 = (const float*)d_in[7];
  const float* b2 = (const float*)d_in[8];
  const float* w3 = (const float*)d_in[9];
  const float* g3 = (const float*)d_in[10];
  const float* b3 = (const float*)d_in[11];
  const float* w4 = (const float*)d_in[12];
  const float* g4 = (const float*)d_in[13];
  const float* b4 = (const float*)d_in[14];
  const float* w5 = (const float*)d_in[15];
  const float* g5 = (const float*)d_in[16];
  const float* b5 = (const float*)d_in[17];
  const float* w6 = (const float*)d_in[18];
  const float* b6 = (const float*)d_in[19];
  const float* dap = (const float*)d_in[20];
  float* out = (float*)d_out;
  char* ws = (char*)d_ws;
  if (ws_size < WS_NEEDED) return;

  uint4* wf1a = (uint4*)(ws + off_wf1a);
  uint4* wf1b = (uint4*)(ws + off_wf1b);
  uint4* wf3 = (uint4*)(ws + off_wf3);
  uint4* wf2 = (uint4*)(ws + off_wf2);
  uint4* wf4 = (uint4*)(ws + off_wf4);
  uint4* wf5 = (uint4*)(ws + off_wf5);
  bf16* f1t = (bf16*)(ws + off_f1t);
  float* y1a = (float*)(ws + off_y1a);
  float* f2t = (float*)(ws + off_f2t);
  bf16* f2s = (bf16*)(ws + off_f2s);
  bf16* y1 = (bf16*)(ws + off_y1);
  bf16* y2 = (bf16*)(ws + off_y2);
  bf16* y3 = (bf16*)(ws + off_y3);
  bf16* y4 = (bf16*)(ws + off_y4);
  bf16* y5 = (bf16*)(ws + off_y5);
  float* y6 = (float*)(ws + off_y6);
  float* st0 = (float*)(ws + off_stats) + 0 * 512;
  float* st1 = (float*)(ws + off_stats) + 1 * 512;
  float* st2 = (float*)(ws + off_stats) + 2 * 512;
  float* st3 = (float*)(ws + off_stats) + 3 * 512;
  float* st4 = (float*)(ws + off_stats) + 4 * 512;

  zero_k<<<10, 256, 0, stream>>>((float*)(ws + off_stats), 2560);

  tr_f2_k<<<576, 256, 0, stream>>>(f2, f2t);
  tr_f1_k<<<576, 256, 0, stream>>>(f1, f1t);
  prep32_k<<<54, 256, 0, stream>>>(w1, wf1a, 3, 256, 0);
  prep32_k<<<54, 256, 0, stream>>>(w1, wf1b, 3, 256, 128);
  prep32_k<<<72, 256, 0, stream>>>(w3, wf3, 4, 128, 0);
  prep16_k<<<54, 256, 0, stream>>>(w2, wf2, 8, 96, 3, 32, 1);
  prep16_k<<<36, 256, 0, stream>>>(w4, wf4, 4, 128, 2, 64, 2);
  prep_w5_k<<<16, 256, 0, stream>>>(w5, wf5);

  sample_k<<<3528, 256, 0, stream>>>(f2t, coords, f2s);

  // conv1 f1-half (shared across 49 displacements), f32 NHWC out
  conv32_k<96, 3, 2, 3, 4, 2, true, false, false><<<36, 256, 0, stream>>>(
      f1t, wf1a, y1a, nullptr, nullptr, nullptr, 2, Hh, Ww, 1);
  // conv1 f2-half + base
  conv32_k<96, 3, 2, 3, 4, 2, false, true, false><<<1764, 256, 0, stream>>>(
      f2s, wf1b, y1, y1a, nullptr, nullptr, Nn, Hh, Ww, DD);

  stats_k<96, 192><<<112, 192, 0, stream>>>(y1, st0, Nn * HW);
  bnfin_k<<<1, 256, 0, stream>>>(st0, g1, b1, st0 + 256, 96, 1.f / (98.f * 4608.f));

  // conv2 stride 2 (bn1 fused on input staging)
  conv16_k<128, 8, 3, 4, 2, 3, 2, 96, 32, 3, 1, true><<<1176, 256, 0, stream>>>(
      y1, wf2, y2, st0 + 256, st0 + 256 + 96, Nn, H2, W2, Hh, Ww);
  stats_k<128, 256><<<112, 256, 0, stream>>>(y2, st1, Nn * HW2);
  bnfin_k<<<1, 256, 0, stream>>>(st1, g2, b2, st1 + 256, 128, 1.f / (98.f * 1152.f));

  // conv3 (bn2 fused)
  conv32_k<128, 4, 3, 2, 2, 3, false, false, true><<<588, 256, 0, stream>>>(
      y2, wf3, y3, nullptr, st1 + 256, st1 + 256 + 128, Nn, H2, W2, 1);
  stats_k<128, 256><<<112, 256, 0, stream>>>(y3, st2, Nn * HW2);
  bnfin_k<<<1, 256, 0, stream>>>(st2, g3, b3, st2 + 256, 128, 1.f / (98.f * 1152.f));

  // conv4 (bn3 fused)
  conv16_k<64, 4, 3, 4, 4, 3, 1, 128, 64, 2, 2, true><<<588, 256, 0, stream>>>(
      y3, wf4, y4, st2 + 256, st2 + 256 + 128, Nn, H2, W2, H2, W2);
  stats_k<64, 256><<<112, 256, 0, stream>>>(y4, st3, Nn * HW2);
  bnfin_k<<<1, 256, 0, stream>>>(st3, g4, b4, st3 + 256, 64, 1.f / (98.f * 1152.f));

  // deconv (bn4 fused)
  deconv16_k<<<588, 256, 0, stream>>>(y4, wf5, y5, st3 + 256, st3 + 256 + 64);
  stats_k<32, 256><<<112, 256, 0, stream>>>(y5, st4, Nn * HW);
  bnfin_k<<<1, 256, 0, stream>>>(st4, g5, b5, st4 + 256, 32, 1.f / (98.f * 4608.f));

  // conv6 (bn5 fused) + bias -> f32
  conv6_k<<<1764, 256, 0, stream>>>(y5, w6, b6, st4 + 256, st4 + 256 + 32, y6);

  // DAP
  dap_k<<<1764, 256, 0, stream>>>(y6, dap, out);
}

// Round 3
// 814.151 us; speedup vs baseline: 7.0328x; 1.4975x over previous
//
#include <hip/hip_runtime.h>
#include <hip/hip_bf16.h>

using bf16 = __hip_bfloat16;
typedef __attribute__((ext_vector_type(8))) short s8v;
typedef __attribute__((ext_vector_type(4))) float f4v;
typedef __attribute__((ext_vector_type(16))) float f16v;

static constexpr int Bb = 2, Hh = 48, Ww = 96;
static constexpr int HW = Hh * Ww;              // 4608
static constexpr int DD = 49, Nn = Bb * DD;     // 98
static constexpr int H2 = 24, W2 = 48, HW2 = H2 * W2;

// ---------------- workspace layout (bytes) ----------------
static constexpr size_t off_wf1a = 0;                 // 221184
static constexpr size_t off_wf1b = 221184;            // 221184
static constexpr size_t off_wf3  = 442368;            // 294912
static constexpr size_t off_wf2  = 737280;            // 221184
static constexpr size_t off_wf4  = 958464;            // 147456
static constexpr size_t off_wf5  = 1105920;           // 65536
static constexpr size_t off_f1t  = 1171456;           // bf16 [2][4608][128] = 2359296
static constexpr size_t off_y1a  = 3530752;           // f32  [2][4608][96]  = 3538944
static constexpr size_t off_stats= 7069696;           // 5*2048
static constexpr size_t off_f2s  = 7079936;           // bf16 [98][4608][128] = 115605504
static constexpr size_t off_y1   = 122685440;         // bf16 [98][4608][96] = 86704128
static constexpr size_t off_f2t  = off_y1;            // f32 [2][4608][128] (dead before y1 written)
static constexpr size_t off_y2   = off_f2s;                   // bf16 [98][1152][128]
static constexpr size_t off_y3   = off_f2s + 28901376;        // bf16 [98][1152][128]
static constexpr size_t off_y4   = off_f2s + 57802752;        // bf16 [98][1152][64]
static constexpr size_t off_y5   = off_f2s + 72253440;        // bf16 [98][4608][32]
static constexpr size_t off_y6   = off_f2s + 101154816;       // f32 [98][4608]
static constexpr size_t WS_NEEDED = 209389568;

// ---------------- helpers ----------------
__device__ __forceinline__ float bf2f(unsigned short h) {
  return __uint_as_float(((unsigned)h) << 16);
}
__device__ __forceinline__ unsigned short f2bf(float f) {
  __hip_bfloat16 h = __float2bfloat16(f);
  union { __hip_bfloat16 x; unsigned short u; } cv; cv.x = h; return cv.u;
}
template<bool EN>
__device__ __forceinline__ uint4 bn8(uint4 v, const float* a, const float* b, int c0) {
  if constexpr (!EN) return v;
  union { uint4 u; unsigned short h[8]; } X; X.u = v;
#pragma unroll
  for (int i = 0; i < 8; ++i) {
    float f = fmaxf(bf2f(X.h[i]) * a[c0 + i] + b[c0 + i], 0.f);
    X.h[i] = f2bf(f);
  }
  return X.u;
}

// ---------------- small utility kernels ----------------
__global__ __launch_bounds__(256) void zero_k(float* __restrict__ p, int n) {
  int i = blockIdx.x * 256 + threadIdx.x;
  if (i < n) p[i] = 0.f;
}

// f2 [2][128][4608] f32 -> f2t [2][4608][128] f32
__global__ __launch_bounds__(256) void tr_f2_k(const float* __restrict__ f2, float* __restrict__ f2t) {
  int o = blockIdx.x * 256 + threadIdx.x;
  if (o >= 2 * HW * 16) return;
  int c8 = o & 15; int pos = (o >> 4) % HW; int b = o / (HW * 16);
  float v[8];
#pragma unroll
  for (int i = 0; i < 8; ++i) v[i] = f2[((size_t)(b * 128 + c8 * 8 + i)) * HW + pos];
  float* dst = f2t + ((size_t)b * HW + pos) * 128 + c8 * 8;
#pragma unroll
  for (int i = 0; i < 8; ++i) dst[i] = v[i];
}

// f1 [2][128][4608] f32 -> f1t [2][4608][128] bf16
__global__ __launch_bounds__(256) void tr_f1_k(const float* __restrict__ f1, bf16* __restrict__ f1t) {
  int o = blockIdx.x * 256 + threadIdx.x;
  if (o >= 2 * HW * 16) return;
  int c8 = o & 15; int pos = (o >> 4) % HW; int b = o / (HW * 16);
  union { uint4 u; unsigned short h[8]; } Y;
#pragma unroll
  for (int i = 0; i < 8; ++i) Y.h[i] = f2bf(f1[((size_t)(b * 128 + c8 * 8 + i)) * HW + pos]);
  *(uint4*)(f1t + ((size_t)b * HW + pos) * 128 + c8 * 8) = Y.u;
}

// weight prep: frag-ordered for 32x32x16 path.  [khw][cih][ks][nt][lh][ocl]x8bf16
__global__ __launch_bounds__(256)
void prep32_k(const float* __restrict__ w, uint4* __restrict__ wf, int NT, int CINT, int ciOff) {
  int idx = blockIdx.x * 256 + threadIdx.x;
  int total = 9 * 2 * 4 * NT * 64;
  if (idx >= total) return;
  int ocl = idx & 31; int lh = (idx >> 5) & 1;
  int q = idx >> 6; int nt = q % NT; int rest = q / NT;
  int ks = rest & 3; int cih = (rest >> 2) & 1; int khw = rest >> 3;
  int oc = nt * 32 + ocl;
  union { uint4 u; unsigned short h[8]; } Y;
#pragma unroll
  for (int i = 0; i < 8; ++i) {
    int ci = ciOff + cih * 64 + ks * 16 + lh * 8 + i;
    Y.h[i] = f2bf(w[((size_t)oc * CINT + ci) * 9 + khw]);
  }
  wf[idx] = Y.u;
}

// frag-ordered for 16x16x32 path.  [khw][st][ks][nt][lg][ocl]x8bf16
__global__ __launch_bounds__(256)
void prep16_k(const float* __restrict__ w, uint4* __restrict__ wf, int NT, int CINT,
              int NSTAGE, int CPS, int KPS) {
  int idx = blockIdx.x * 256 + threadIdx.x;
  int total = 9 * NSTAGE * KPS * NT * 64;
  if (idx >= total) return;
  int ocl = idx & 15; int lg = (idx >> 4) & 3;
  int q = idx >> 6; int nt = q % NT; int q2 = q / NT;
  int ks = q2 % KPS; int q3 = q2 / KPS;
  int st = q3 % NSTAGE; int khw = q3 / NSTAGE;
  int oc = nt * 16 + ocl;
  union { uint4 u; unsigned short h[8]; } Y;
#pragma unroll
  for (int i = 0; i < 8; ++i) {
    int ci = st * CPS + ks * 32 + lg * 8 + i;
    Y.h[i] = f2bf(w[((size_t)oc * CINT + ci) * 9 + khw]);
  }
  wf[idx] = Y.u;
}

// w5 [64ci][32oc][4][4] -> frag-ordered [p][ks][nt][lg][ocl]x8
__global__ __launch_bounds__(256)
void prep_w5_k(const float* __restrict__ w5, uint4* __restrict__ wf) {
  int idx = blockIdx.x * 256 + threadIdx.x;
  if (idx >= 4096) return;
  int ocl = idx & 15; int lg = (idx >> 4) & 3;
  int nt = (idx >> 6) & 1; int ks = (idx >> 7) & 7; int p = idx >> 10;
  int ph = p >> 1, pw = p & 1;
  int t = ks >> 2, u = (ks >> 1) & 1;
  int kh = 3 - ph - 2 * t, kw = 3 - pw - 2 * u;
  int oc = nt * 16 + ocl;
  union { uint4 u4; unsigned short h[8]; } Y;
#pragma unroll
  for (int i = 0; i < 8; ++i) {
    int ci = (ks & 1) * 32 + lg * 8 + i;
    Y.h[i] = f2bf(w5[(((size_t)ci * 32 + oc) * 4 + kh) * 4 + kw]);
  }
  wf[idx] = Y.u4;
}

// ---------------- correlation sampling -> f2s NHWC bf16 ----------------
__global__ __launch_bounds__(256)
void sample_k(const float* __restrict__ f2t, const float* __restrict__ coords,
              bf16* __restrict__ f2s) {
  int wv = blockIdx.x * 4 + (threadIdx.x >> 6);
  int lane = threadIdx.x & 63;
  int p0 = wv * 32;
  for (int k = 0; k < 32; ++k) {
    int P = p0 + k;
    int hw = P % HW; int n = P / HW;
    int b = n / DD, d = n % DD;
    float gx = coords[(size_t)b * 2 * HW + hw] + (float)(d / 7 - 3);
    float gy = coords[((size_t)b * 2 + 1) * HW + hw] + (float)(d % 7 - 3);
    float x0f = floorf(gx), y0f = floorf(gy);
    float wx = gx - x0f, wy = gy - y0f;
    int x0 = (int)x0f, y0 = (int)y0f;
    const float* base = f2t + (size_t)b * HW * 128;
    float r0 = 0.f, r1 = 0.f;
#pragma unroll
    for (int c = 0; c < 4; ++c) {
      int xi = x0 + (c & 1), yi = y0 + (c >> 1);
      float wgt = ((c & 1) ? wx : 1.f - wx) * ((c >> 1) ? wy : 1.f - wy);
      if (xi < 0 || xi >= Ww || yi < 0 || yi >= Hh) wgt = 0.f;
      int xc = min(max(xi, 0), Ww - 1), yc = min(max(yi, 0), Hh - 1);
      const float* pv = base + ((size_t)(yc * Ww + xc)) * 128 + 2 * lane;
      r0 += wgt * pv[0];
      r1 += wgt * pv[1];
    }
    unsigned pack = (unsigned)f2bf(r0) | ((unsigned)f2bf(r1) << 16);
    ((unsigned*)f2s)[(size_t)P * 64 + lane] = pack;
  }
}

// ---------------- 32x32x16 MFMA conv (stride 1, CIN=128) ----------------
template<int COUT, int NT, int MT, int NB, int GR, int GC, bool OUTF32, bool HAS_BASE,
         bool HAS_BN, bool HAS_STATS>
__global__ __launch_bounds__(((GR * GC) / MT) * (NT / NB) * 64)
void conv32_k(const bf16* __restrict__ in, const uint4* __restrict__ wf,
              void* __restrict__ outv, const float* __restrict__ base,
              const float* __restrict__ bn_a, const float* __restrict__ bn_b,
              float* __restrict__ stats,
              int N, int H, int W, int DIV) {
  constexpr int NW = ((GR * GC) / MT) * (NT / NB);
  constexpr int BR = GR * 2, BC = GC * 16;
  constexpr int IR = BR + 2, IC = BC + 2;
  constexpr int INB = IR * IC * 128;
  constexpr int WCH = NT * 256;          // 16B chunks per (khw,cih) slice
  __shared__ __align__(16) char lds[INB + WCH * 16];

  const int tid = threadIdx.x;
  const int lane = tid & 63;
  const int wv = tid >> 6;
  const int lm = lane & 31, lh = lane >> 5;
  const int dh = lm >> 4, dw = lm & 15;
  constexpr int NG = NT / NB;
  const int mg = wv / NG, ng = wv % NG;

  const int tW = W / BC, tH = H / BR;
  const int tile = blockIdx.x % (tH * tW);
  const int n = blockIdx.x / (tH * tW);
  const int oh0 = (tile / tW) * BR, ow0 = (tile % tW) * BC;
  const size_t inbase = (size_t)n * H * W * 128;

  int trA[MT], tcA[MT];
#pragma unroll
  for (int i = 0; i < MT; ++i) { int mt = mg * MT + i; trA[i] = mt / GC; tcA[i] = mt % GC; }
  const int bb0 = INB + lh * 512 + lm * 16;

  f16v acc[MT][NB];
#pragma unroll
  for (int i = 0; i < MT; ++i)
#pragma unroll
    for (int j = 0; j < NB; ++j)
#pragma unroll
      for (int r = 0; r < 16; ++r) acc[i][j][r] = 0.f;

  for (int cih = 0; cih < 2; ++cih) {
    for (int khw = 0; khw < 9; ++khw) {
      __syncthreads();
      if (khw == 0) {
        for (int idx = tid; idx < IR * IC * 8; idx += NW * 64) {
          int h8 = idx & 7;
          int icl = (idx >> 3) % IC;
          int ihl = (idx >> 3) / IC;
          int ih = oh0 - 1 + ihl, iw = ow0 - 1 + icl;
          uint4 v = make_uint4(0u, 0u, 0u, 0u);
          if (ih >= 0 && ih < H && iw >= 0 && iw < W) {
            v = *(const uint4*)(in + inbase + ((size_t)(ih * W + iw)) * 128 + cih * 64 + h8 * 8);
            v = bn8<HAS_BN>(v, bn_a, bn_b, cih * 64 + h8 * 8);
          }
          int bbyte = (ihl * IC + icl) * 128 + h8 * 16;
          bbyte ^= (icl & 7) << 4;
          *(uint4*)(lds + bbyte) = v;
        }
      }
      {
        const uint4* src = wf + (khw * 2 + cih) * WCH;
        for (int idx = tid; idx < WCH; idx += NW * 64)
          *(uint4*)(lds + INB + idx * 16) = src[idx];
      }
      __syncthreads();
      const int kh = khw / 3, kw = khw % 3;
#pragma unroll
      for (int ks = 0; ks < 4; ++ks) {
        s8v Af[MT], Bf[NB];
#pragma unroll
        for (int i = 0; i < MT; ++i) {
          int rl = trA[i] * 2 + dh + kh;
          int cl = tcA[i] * 16 + dw + kw;
          int bbyte = (rl * IC + cl) * 128 + ks * 32 + lh * 16;
          bbyte ^= (cl & 7) << 4;
          Af[i] = *(const s8v*)(lds + bbyte);
        }
#pragma unroll
        for (int j = 0; j < NB; ++j)
          Bf[j] = *(const s8v*)(lds + bb0 + (ks * NT + ng * NB + j) * 1024);
#pragma unroll
        for (int i = 0; i < MT; ++i)
#pragma unroll
          for (int j = 0; j < NB; ++j)
            acc[i][j] = __builtin_amdgcn_mfma_f32_32x32x16_bf16(Af[i], Bf[j], acc[i][j], 0, 0, 0);
      }
    }
  }

  const size_t obase = (size_t)n * H * W * COUT;
  const float* bptr = nullptr;
  if constexpr (HAS_BASE) bptr = base + (size_t)(n / DIV) * H * W * COUT;

  float sacc[NB], qacc[NB];
#pragma unroll
  for (int j = 0; j < NB; ++j) { sacc[j] = 0.f; qacc[j] = 0.f; }

#pragma unroll
  for (int i = 0; i < MT; ++i) {
#pragma unroll
    for (int j = 0; j < NB; ++j) {
      int oc = (ng * NB + j) * 32 + lm;
#pragma unroll
      for (int r = 0; r < 16; ++r) {
        int row = (r & 3) + 8 * (r >> 2) + 4 * lh;
        int oh = oh0 + trA[i] * 2 + (row >> 4);
        int ow = ow0 + tcA[i] * 16 + (row & 15);
        size_t pix = (size_t)(oh * W + ow);
        float v = acc[i][j][r];
        if constexpr (HAS_BASE) v += bptr[pix * COUT + oc];
        if constexpr (HAS_STATS) { sacc[j] += v; qacc[j] += v * v; }
        if constexpr (OUTF32) ((float*)outv)[obase + pix * COUT + oc] = v;
        else ((bf16*)outv)[obase + pix * COUT + oc] = __float2bfloat16(v);
      }
    }
  }

  if constexpr (HAS_STATS) {
    __shared__ float sred[2 * COUT];
    for (int i = tid; i < 2 * COUT; i += NW * 64) sred[i] = 0.f;
    __syncthreads();
#pragma unroll
    for (int j = 0; j < NB; ++j) {
      int oc = (ng * NB + j) * 32 + lm;
      atomicAdd(&sred[oc], sacc[j]);
      atomicAdd(&sred[COUT + oc], qacc[j]);
    }
    __syncthreads();
    for (int i = tid; i < 2 * COUT; i += NW * 64) atomicAdd(&stats[i], sred[i]);
  }
}

// ---------------- 16x16x32 MFMA conv (stride 1 or 2) ----------------
template<int COUT, int NT, int MT, int NB, int GR, int GC, int STRIDE,
         int CINT, int CPS, int NSTAGE, int KPS, bool HAS_BN, bool HAS_STATS>
__global__ __launch_bounds__(((GR * GC) / MT) * (NT / NB) * 64)
void conv16_k(const bf16* __restrict__ in, const uint4* __restrict__ wf,
              bf16* __restrict__ out, const float* __restrict__ bn_a,
              const float* __restrict__ bn_b, float* __restrict__ stats,
              int N, int HO, int WO, int HI, int WI) {
  constexpr int NW = ((GR * GC) / MT) * (NT / NB);
  constexpr int BR = GR, BC = GC * 16;
  constexpr int IR = STRIDE * (BR - 1) + 3;
  constexpr int IC = STRIDE * (BC - 1) + 3 + (STRIDE == 2 ? 1 : 0);
  constexpr int ROWB = CPS * 2;
  constexpr int SLOTM = ROWB / 16 - 1;
  constexpr int INB = IR * IC * ROWB;
  constexpr int WCH = KPS * NT * 64;
  __shared__ __align__(16) char lds[INB + WCH * 16];

  const int tid = threadIdx.x;
  const int lane = tid & 63;
  const int wv = tid >> 6;
  const int lm = lane & 15, lg = lane >> 4;
  constexpr int NG = NT / NB;
  const int mg = wv / NG, ng = wv % NG;

  const int tW = WO / BC, tH = HO / BR;
  const int tile = blockIdx.x % (tH * tW);
  const int n = blockIdx.x / (tH * tW);
  const int oh0 = (tile / tW) * BR, ow0 = (tile % tW) * BC;
  const int ih0 = STRIDE * oh0 - 1, iw0 = STRIDE * ow0 - 1;
  const size_t inbase = (size_t)n * HI * WI * CINT;

  int trA[MT], tcA[MT];
#pragma unroll
  for (int i = 0; i < MT; ++i) { int mt = mg * MT + i; trA[i] = mt / GC; tcA[i] = mt % GC; }

  f4v acc[MT][NB];
#pragma unroll
  for (int i = 0; i < MT; ++i)
#pragma unroll
    for (int j = 0; j < NB; ++j)
#pragma unroll
      for (int r = 0; r < 4; ++r) acc[i][j][r] = 0.f;

  for (int st = 0; st < NSTAGE; ++st) {
    for (int khw = 0; khw < 9; ++khw) {
      __syncthreads();
      if (khw == 0) {
        for (int idx = tid; idx < IR * IC * (CPS / 8); idx += NW * 64) {
          int h8 = idx % (CPS / 8);
          int rest = idx / (CPS / 8);
          int icl = rest % IC;
          int ihl = rest / IC;
          int ih = ih0 + ihl, iw = iw0 + icl;
          uint4 v = make_uint4(0u, 0u, 0u, 0u);
          if (ih >= 0 && ih < HI && iw >= 0 && iw < WI) {
            v = *(const uint4*)(in + inbase + ((size_t)(ih * WI + iw)) * CINT + st * CPS + h8 * 8);
            v = bn8<HAS_BN>(v, bn_a, bn_b, st * CPS + h8 * 8);
          }
          int bbyte = (ihl * IC + icl) * ROWB + h8 * 16;
          bbyte ^= ((icl >> (STRIDE - 1)) & SLOTM) << 4;
          *(uint4*)(lds + bbyte) = v;
        }
      }
      {
        const uint4* src = wf + (khw * NSTAGE + st) * WCH;
        for (int idx = tid; idx < WCH; idx += NW * 64)
          *(uint4*)(lds + INB + idx * 16) = src[idx];
      }
      __syncthreads();
      const int kh = khw / 3, kw = khw % 3;
#pragma unroll
      for (int ks = 0; ks < KPS; ++ks) {
        s8v Af[MT], Bf[NB];
#pragma unroll
        for (int i = 0; i < MT; ++i) {
          int rl = STRIDE * trA[i] + kh;
          int cl = STRIDE * (tcA[i] * 16 + lm) + kw;
          int bbyte = (rl * IC + cl) * ROWB + ks * 64 + lg * 16;
          bbyte ^= ((cl >> (STRIDE - 1)) & SLOTM) << 4;
          Af[i] = *(const s8v*)(lds + bbyte);
        }
#pragma unroll
        for (int j = 0; j < NB; ++j)
          Bf[j] = *(const s8v*)(lds + INB + ((ks * NT + ng * NB + j) * 64 + lg * 16 + lm) * 16);
#pragma unroll
        for (int i = 0; i < MT; ++i)
#pragma unroll
          for (int j = 0; j < NB; ++j)
            acc[i][j] = __builtin_amdgcn_mfma_f32_16x16x32_bf16(Af[i], Bf[j], acc[i][j], 0, 0, 0);
      }
    }
  }

  const size_t obase = (size_t)n * HO * WO * COUT;
  float sacc[NB], qacc[NB];
#pragma unroll
  for (int j = 0; j < NB; ++j) { sacc[j] = 0.f; qacc[j] = 0.f; }

#pragma unroll
  for (int i = 0; i < MT; ++i) {
#pragma unroll
    for (int j = 0; j < NB; ++j) {
      int oc = (ng * NB + j) * 16 + lm;
#pragma unroll
      for (int r = 0; r < 4; ++r) {
        int oh = oh0 + trA[i];
        int ow = ow0 + tcA[i] * 16 + lg * 4 + r;
        float v = acc[i][j][r];
        if constexpr (HAS_STATS) { sacc[j] += v; qacc[j] += v * v; }
        out[obase + (size_t)(oh * WO + ow) * COUT + oc] = __float2bfloat16(v);
      }
    }
  }

  if constexpr (HAS_STATS) {
    __shared__ float sred[2 * COUT];
    for (int i = tid; i < 2 * COUT; i += NW * 64) sred[i] = 0.f;
    __syncthreads();
#pragma unroll
    for (int j = 0; j < NB; ++j) {
      int oc = (ng * NB + j) * 16 + lm;
      atomicAdd(&sred[oc], sacc[j]);
      atomicAdd(&sred[COUT + oc], qacc[j]);
    }
    __syncthreads();
    for (int i = tid; i < 2 * COUT; i += NW * 64) atomicAdd(&stats[i], sred[i]);
  }
}

// ---------------- deconv (ConvTranspose2d k4 s2 p1, 64->32) via 16x16x32 ----------------
__global__ __launch_bounds__(256)
void deconv16_k(const bf16* __restrict__ in, const uint4* __restrict__ wf5,
                bf16* __restrict__ out, const float* __restrict__ a4,
                const float* __restrict__ b4, float* __restrict__ stats) {
  constexpr int IR = 6, IC = 50, INB = IR * IC * 128;
  __shared__ __align__(16) char lds[INB + 16384];
  __shared__ float sred[64];
  const int tid = threadIdx.x;
  const int lane = tid & 63, wv = tid >> 6;
  const int lm = lane & 15, lg = lane >> 4;
  const int n = blockIdx.x / 6;
  const int qh0 = (blockIdx.x % 6) * 4;
  const size_t ibase = (size_t)n * HW2 * 64;

  for (int idx = tid; idx < 64; idx += 256) sred[idx] = 0.f;

  for (int idx = tid; idx < IR * IC * 8; idx += 256) {
    int h8 = idx & 7; int icl = (idx >> 3) % IC; int ihl = (idx >> 3) / IC;
    int ih = qh0 - 1 + ihl, iw = -1 + icl;
    uint4 v = make_uint4(0u, 0u, 0u, 0u);
    if (ih >= 0 && ih < H2 && iw >= 0 && iw < W2) {
      v = *(const uint4*)(in + ibase + ((size_t)(ih * W2 + iw)) * 64 + h8 * 8);
      v = bn8<true>(v, a4, b4, h8 * 8);
    }
    int bbyte = (ihl * IC + icl) * 128 + h8 * 16;
    bbyte ^= (icl & 7) << 4;
    *(uint4*)(lds + bbyte) = v;
  }
  int trA[3], tcA[3];
#pragma unroll
  for (int i = 0; i < 3; ++i) { int mt = wv * 3 + i; trA[i] = mt / 3; tcA[i] = mt % 3; }

  float sacc[2], qacc[2];
  sacc[0] = sacc[1] = qacc[0] = qacc[1] = 0.f;

  for (int p = 0; p < 4; ++p) {
    __syncthreads();
    for (int idx = tid; idx < 1024; idx += 256)
      *(uint4*)(lds + INB + idx * 16) = wf5[p * 1024 + idx];
    __syncthreads();
    const int ph = p >> 1, pw = p & 1;
    f4v acc[3][2];
#pragma unroll
    for (int i = 0; i < 3; ++i)
#pragma unroll
      for (int j = 0; j < 2; ++j)
#pragma unroll
        for (int r = 0; r < 4; ++r) acc[i][j][r] = 0.f;
#pragma unroll
    for (int ks = 0; ks < 8; ++ks) {
      int t = ks >> 2, u = (ks >> 1) & 1, cb = ks & 1;
      s8v Af[3], Bf[2];
#pragma unroll
      for (int i = 0; i < 3; ++i) {
        int rl = trA[i] + t + ph;
        int cl = tcA[i] * 16 + lm + u + pw;
        int bbyte = (rl * IC + cl) * 128 + cb * 64 + lg * 16;
        bbyte ^= (cl & 7) << 4;
        Af[i] = *(const s8v*)(lds + bbyte);
      }
#pragma unroll
      for (int j = 0; j < 2; ++j)
        Bf[j] = *(const s8v*)(lds + INB + ((ks * 2 + j) * 64 + lg * 16 + lm) * 16);
#pragma unroll
      for (int i = 0; i < 3; ++i)
#pragma unroll
        for (int j = 0; j < 2; ++j)
          acc[i][j] = __builtin_amdgcn_mfma_f32_16x16x32_bf16(Af[i], Bf[j], acc[i][j], 0, 0, 0);
    }
#pragma unroll
    for (int i = 0; i < 3; ++i) {
#pragma unroll
      for (int j = 0; j < 2; ++j) {
        int oc = j * 16 + lm;
#pragma unroll
        for (int r = 0; r < 4; ++r) {
          int qh = qh0 + trA[i];
          int qw = tcA[i] * 16 + lg * 4 + r;
          int oh = 2 * qh + ph, ow = 2 * qw + pw;
          float v = acc[i][j][r];
          sacc[j] += v; qacc[j] += v * v;
          out[((size_t)n * HW + oh * Ww + ow) * 32 + oc] = __float2bfloat16(v);
        }
      }
    }
  }

  __syncthreads();
#pragma unroll
  for (int j = 0; j < 2; ++j) {
    int oc = j * 16 + lm;
    atomicAdd(&sred[oc], sacc[j]);
    atomicAdd(&sred[32 + oc], qacc[j]);
  }
  __syncthreads();
  for (int i = tid; i < 64; i += 256) atomicAdd(&stats[i], sred[i]);
}

// ---------------- BN finalize ----------------
__global__ void bnfin_k(const float* __restrict__ sums, const float* __restrict__ gamma,
                        const float* __restrict__ beta, float* __restrict__ ab, int C, float invCnt) {
  int c = blockIdx.x * blockDim.x + threadIdx.x;
  if (c >= C) return;
  float mean = sums[c] * invCnt;
  float var = sums[C + c] * invCnt - mean * mean;
  float a = gamma[c] * rsqrtf(var + 1e-5f);
  ab[c] = a;
  ab[C + c] = beta[c] - mean * a;
}

// ---------------- conv6 (32->1, 3x3, fused bn5) ----------------
__global__ __launch_bounds__(256)
void conv6_k(const bf16* __restrict__ y5, const float* __restrict__ w6,
             const float* __restrict__ b6, const float* __restrict__ a5,
             const float* __restrict__ bb5, float* __restrict__ y6) {
  int o = blockIdx.x * 256 + threadIdx.x;
  if (o >= Nn * HW) return;
  int hw = o % HW; int n = o / HW;
  int h = hw / Ww, w = hw % Ww;
  float acc = b6[0];
  for (int kh = 0; kh < 3; ++kh) {
    int ih = h - 1 + kh; if (ih < 0 || ih >= Hh) continue;
    for (int kw = 0; kw < 3; ++kw) {
      int iw = w - 1 + kw; if (iw < 0 || iw >= Ww) continue;
      const bf16* p = y5 + ((size_t)n * HW + ih * Ww + iw) * 32;
      int khw = kh * 3 + kw;
#pragma unroll
      for (int c8 = 0; c8 < 4; ++c8) {
        union { uint4 u; unsigned short hh[8]; } X;
        X.u = *(const uint4*)(p + c8 * 8);
#pragma unroll
        for (int i = 0; i < 8; ++i) {
          int c = c8 * 8 + i;
          float f = fmaxf(bf2f(X.hh[i]) * a5[c] + bb5[c], 0.f);
          acc += f * w6[c * 9 + khw];
        }
      }
    }
  }
  y6[o] = acc;
}

// ---------------- DAP ----------------
__global__ __launch_bounds__(256)
void dap_k(const float* __restrict__ y6, const float* __restrict__ dap, float* __restrict__ out) {
  int o = blockIdx.x * 256 + threadIdx.x;
  if (o >= Bb * DD * HW) return;
  int hw = o % HW;
  int e = (o / HW) % DD;
  int b = o / (HW * DD);
  float s = 0.f;
#pragma unroll 7
  for (int d = 0; d < DD; ++d) s += dap[e * DD + d] * y6[((size_t)(b * DD + d)) * HW + hw];
  out[o] = s;
}

// ---------------- host launch ----------------
extern "C" void kernel_launch(void* const* d_in, const int* in_sizes, int n_in,
                              void* d_out, int out_size, void* d_ws, size_t ws_size,
                              hipStream_t stream) {
  const float* f1 = (const float*)d_in[0];
  const float* f2 = (const float*)d_in[1];
  const float* coords = (const float*)d_in[2];
  const float* w1 = (const float*)d_in[3];
  const float* g1 = (const float*)d_in[4];
  const float* b1 = (const float*)d_in[5];
  const float* w2 = (const float*)d_in[6];
  const float* g2 = (const float*)d_in[7];
  const float* b2 = (const float*)d_in[8];
  const float* w3 = (const float*)d_in[9];
  const float* g3 = (const float*)d_in[10];
  const float* b3 = (const float*)d_in[11];
  const float* w4 = (const float*)d_in[12];
  const float* g4 = (const float*)d_in[13];
  const float* b4 = (const float*)d_in[14];
  const float* w5 = (const float*)d_in[15];
  const float* g5 = (const float*)d_in[16];
  const float* b5 = (const float*)d_in[17];
  const float* w6 = (const float*)d_in[18];
  const float* b6 = (const float*)d_in[19];
  const float* dap = (const float*)d_in[20];
  float* out = (float*)d_out;
  char* ws = (char*)d_ws;
  if (ws_size < WS_NEEDED) return;

  uint4* wf1a = (uint4*)(ws + off_wf1a);
  uint4* wf1b = (uint4*)(ws + off_wf1b);
  uint4* wf3 = (uint4*)(ws + off_wf3);
  uint4* wf2 = (uint4*)(ws + off_wf2);
  uint4* wf4 = (uint4*)(ws + off_wf4);
  uint4* wf5 = (uint4*)(ws + off_wf5);
  bf16* f1t = (bf16*)(ws + off_f1t);
  float* y1a = (float*)(ws + off_y1a);
  float* f2t = (float*)(ws + off_f2t);
  bf16* f2s = (bf16*)(ws + off_f2s);
  bf16* y1 = (bf16*)(ws + off_y1);
  bf16* y2 = (bf16*)(ws + off_y2);
  bf16* y3 = (bf16*)(ws + off_y3);
  bf16* y4 = (bf16*)(ws + off_y4);
  bf16* y5 = (bf16*)(ws + off_y5);
  float* y6 = (float*)(ws + off_y6);
  float* st0 = (float*)(ws + off_stats) + 0 * 512;
  float* st1 = (float*)(ws + off_stats) + 1 * 512;
  float* st2 = (float*)(ws + off_stats) + 2 * 512;
  float* st3 = (float*)(ws + off_stats) + 3 * 512;
  float* st4 = (float*)(ws + off_stats) + 4 * 512;

  zero_k<<<10, 256, 0, stream>>>((float*)(ws + off_stats), 2560);

  tr_f2_k<<<576, 256, 0, stream>>>(f2, f2t);
  tr_f1_k<<<576, 256, 0, stream>>>(f1, f1t);
  prep32_k<<<54, 256, 0, stream>>>(w1, wf1a, 3, 256, 0);
  prep32_k<<<54, 256, 0, stream>>>(w1, wf1b, 3, 256, 128);
  prep32_k<<<72, 256, 0, stream>>>(w3, wf3, 4, 128, 0);
  prep16_k<<<54, 256, 0, stream>>>(w2, wf2, 8, 96, 3, 32, 1);
  prep16_k<<<36, 256, 0, stream>>>(w4, wf4, 4, 128, 2, 64, 2);
  prep_w5_k<<<16, 256, 0, stream>>>(w5, wf5);

  sample_k<<<3528, 256, 0, stream>>>(f2t, coords, f2s);

  // conv1 f1-half (shared across 49 displacements), f32 NHWC out
  conv32_k<96, 3, 2, 3, 4, 2, true, false, false, false><<<36, 256, 0, stream>>>(
      f1t, wf1a, y1a, nullptr, nullptr, nullptr, nullptr, 2, Hh, Ww, 1);
  // conv1 f2-half + base, fused BN1 stats
  conv32_k<96, 3, 2, 3, 4, 2, false, true, false, true><<<1764, 256, 0, stream>>>(
      f2s, wf1b, y1, y1a, nullptr, nullptr, st0, Nn, Hh, Ww, DD);
  bnfin_k<<<1, 256, 0, stream>>>(st0, g1, b1, st0 + 256, 96, 1.f / (98.f * 4608.f));

  // conv2 stride 2 (bn1 fused on input staging), fused BN2 stats
  conv16_k<128, 8, 3, 4, 2, 3, 2, 96, 32, 3, 1, true, true><<<1176, 256, 0, stream>>>(
      y1, wf2, y2, st0 + 256, st0 + 256 + 96, st1, Nn, H2, W2, Hh, Ww);
  bnfin_k<<<1, 256, 0, stream>>>(st1, g2, b2, st1 + 256, 128, 1.f / (98.f * 1152.f));

  // conv3 (bn2 fused), fused BN3 stats
  conv32_k<128, 4, 3, 2, 2, 3, false, false, true, true><<<588, 256, 0, stream>>>(
      y2, wf3, y3, nullptr, st1 + 256, st1 + 256 + 128, st2, Nn, H2, W2, 1);
  bnfin_k<<<1, 256, 0, stream>>>(st2, g3, b3, st2 + 256, 128, 1.f / (98.f * 1152.f));

  // conv4 (bn3 fused), fused BN4 stats
  conv16_k<64, 4, 3, 4, 4, 3, 1, 128, 64, 2, 2, true, true><<<588, 256, 0, stream>>>(
      y3, wf4, y4, st2 + 256, st2 + 256 + 128, st3, Nn, H2, W2, H2, W2);
  bnfin_k<<<1, 256, 0, stream>>>(st3, g4, b4, st3 + 256, 64, 1.f / (98.f * 1152.f));

  // deconv (bn4 fused), fused BN5 stats
  deconv16_k<<<588, 256, 0, stream>>>(y4, wf5, y5, st3 + 256, st3 + 256 + 64, st4);
  bnfin_k<<<1, 256, 0, stream>>>(st4, g5, b5, st4 + 256, 32, 1.f / (98.f * 4608.f));

  // conv6 (bn5 fused) + bias -> f32
  conv6_k<<<1764, 256, 0, stream>>>(y5, w6, b6, st4 + 256, st4 + 256 + 32, y6);

  // DAP
  dap_k<<<1764, 256, 0, stream>>>(y6, dap, out);
}

// Round 4
// 767.119 us; speedup vs baseline: 7.4640x; 1.0613x over previous
//
#include <hip/hip_runtime.h>
#include <hip/hip_bf16.h>

using bf16 = __hip_bfloat16;
typedef __attribute__((ext_vector_type(8))) short s8v;
typedef __attribute__((ext_vector_type(4))) float f4v;
typedef __attribute__((ext_vector_type(16))) float f16v;

static constexpr int Bb = 2, Hh = 48, Ww = 96;
static constexpr int HW = Hh * Ww;              // 4608
static constexpr int DD = 49, Nn = Bb * DD;     // 98
static constexpr int H2 = 24, W2 = 48, HW2 = H2 * W2;

// ---------------- workspace layout (bytes) ----------------
static constexpr size_t off_wf1a = 0;                 // 221184
static constexpr size_t off_wf1b = 221184;            // 221184
static constexpr size_t off_wf3  = 442368;            // 294912
static constexpr size_t off_wf2  = 737280;            // 221184
static constexpr size_t off_wf4  = 958464;            // 147456
static constexpr size_t off_wf5  = 1105920;           // 65536
static constexpr size_t off_f1t  = 1171456;           // bf16 [2][4608][128] = 2359296
static constexpr size_t off_y1a  = 3530752;           // f32  [2][4608][96]  = 3538944
static constexpr size_t off_stats= 7069696;           // 5*2048
static constexpr size_t off_f2s  = 7079936;           // bf16 [98][4608][128] = 115605504
static constexpr size_t off_y1   = 122685440;         // bf16 [98][4608][96] = 86704128
static constexpr size_t off_f2t  = off_y1;            // f32 [2][4608][128] (dead before y1 written)
static constexpr size_t off_y2   = off_f2s;                   // bf16 [98][1152][128]
static constexpr size_t off_y3   = off_f2s + 28901376;        // bf16 [98][1152][128]
static constexpr size_t off_y4   = off_f2s + 57802752;        // bf16 [98][1152][64]
static constexpr size_t off_y5   = off_f2s + 72253440;        // bf16 [98][4608][32]
static constexpr size_t off_y6   = off_f2s + 101154816;       // f32 [98][4608]
static constexpr size_t WS_NEEDED = 209389568;

// ---------------- helpers ----------------
__device__ __forceinline__ float bf2f(unsigned short h) {
  return __uint_as_float(((unsigned)h) << 16);
}
__device__ __forceinline__ unsigned short f2bf(float f) {
  __hip_bfloat16 h = __float2bfloat16(f);
  union { __hip_bfloat16 x; unsigned short u; } cv; cv.x = h; return cv.u;
}
template<bool EN>
__device__ __forceinline__ uint4 bn8(uint4 v, const float* a, const float* b, int c0) {
  if constexpr (!EN) return v;
  union { uint4 u; unsigned short h[8]; } X; X.u = v;
#pragma unroll
  for (int i = 0; i < 8; ++i) {
    float f = fmaxf(bf2f(X.h[i]) * a[c0 + i] + b[c0 + i], 0.f);
    X.h[i] = f2bf(f);
  }
  return X.u;
}
__device__ __forceinline__ s8v as_s8v(uint4 v) {
  union { uint4 u; s8v s; } cv; cv.u = v; return cv.s;
}

// ---------------- small utility kernels ----------------
__global__ __launch_bounds__(256) void zero_k(float* __restrict__ p, int n) {
  int i = blockIdx.x * 256 + threadIdx.x;
  if (i < n) p[i] = 0.f;
}

// f2 [2][128][4608] f32 -> f2t [2][4608][128] f32
__global__ __launch_bounds__(256) void tr_f2_k(const float* __restrict__ f2, float* __restrict__ f2t) {
  int o = blockIdx.x * 256 + threadIdx.x;
  if (o >= 2 * HW * 16) return;
  int c8 = o & 15; int pos = (o >> 4) % HW; int b = o / (HW * 16);
  float v[8];
#pragma unroll
  for (int i = 0; i < 8; ++i) v[i] = f2[((size_t)(b * 128 + c8 * 8 + i)) * HW + pos];
  float* dst = f2t + ((size_t)b * HW + pos) * 128 + c8 * 8;
#pragma unroll
  for (int i = 0; i < 8; ++i) dst[i] = v[i];
}

// f1 [2][128][4608] f32 -> f1t [2][4608][128] bf16
__global__ __launch_bounds__(256) void tr_f1_k(const float* __restrict__ f1, bf16* __restrict__ f1t) {
  int o = blockIdx.x * 256 + threadIdx.x;
  if (o >= 2 * HW * 16) return;
  int c8 = o & 15; int pos = (o >> 4) % HW; int b = o / (HW * 16);
  union { uint4 u; unsigned short h[8]; } Y;
#pragma unroll
  for (int i = 0; i < 8; ++i) Y.h[i] = f2bf(f1[((size_t)(b * 128 + c8 * 8 + i)) * HW + pos]);
  *(uint4*)(f1t + ((size_t)b * HW + pos) * 128 + c8 * 8) = Y.u;
}

// weight prep: frag-ordered for 32x32x16 path.  [khw][cih][ks][nt][lh][ocl]x8bf16
__global__ __launch_bounds__(256)
void prep32_k(const float* __restrict__ w, uint4* __restrict__ wf, int NT, int CINT, int ciOff) {
  int idx = blockIdx.x * 256 + threadIdx.x;
  int total = 9 * 2 * 4 * NT * 64;
  if (idx >= total) return;
  int ocl = idx & 31; int lh = (idx >> 5) & 1;
  int q = idx >> 6; int nt = q % NT; int rest = q / NT;
  int ks = rest & 3; int cih = (rest >> 2) & 1; int khw = rest >> 3;
  int oc = nt * 32 + ocl;
  union { uint4 u; unsigned short h[8]; } Y;
#pragma unroll
  for (int i = 0; i < 8; ++i) {
    int ci = ciOff + cih * 64 + ks * 16 + lh * 8 + i;
    Y.h[i] = f2bf(w[((size_t)oc * CINT + ci) * 9 + khw]);
  }
  wf[idx] = Y.u;
}

// frag-ordered for 16x16x32 path.  [khw][st][ks][nt][lg][ocl]x8bf16
__global__ __launch_bounds__(256)
void prep16_k(const float* __restrict__ w, uint4* __restrict__ wf, int NT, int CINT,
              int NSTAGE, int CPS, int KPS) {
  int idx = blockIdx.x * 256 + threadIdx.x;
  int total = 9 * NSTAGE * KPS * NT * 64;
  if (idx >= total) return;
  int ocl = idx & 15; int lg = (idx >> 4) & 3;
  int q = idx >> 6; int nt = q % NT; int q2 = q / NT;
  int ks = q2 % KPS; int q3 = q2 / KPS;
  int st = q3 % NSTAGE; int khw = q3 / NSTAGE;
  int oc = nt * 16 + ocl;
  union { uint4 u; unsigned short h[8]; } Y;
#pragma unroll
  for (int i = 0; i < 8; ++i) {
    int ci = st * CPS + ks * 32 + lg * 8 + i;
    Y.h[i] = f2bf(w[((size_t)oc * CINT + ci) * 9 + khw]);
  }
  wf[idx] = Y.u;
}

// w5 [64ci][32oc][4][4] -> frag-ordered [p][ks][nt][lg][ocl]x8
__global__ __launch_bounds__(256)
void prep_w5_k(const float* __restrict__ w5, uint4* __restrict__ wf) {
  int idx = blockIdx.x * 256 + threadIdx.x;
  if (idx >= 4096) return;
  int ocl = idx & 15; int lg = (idx >> 4) & 3;
  int nt = (idx >> 6) & 1; int ks = (idx >> 7) & 7; int p = idx >> 10;
  int ph = p >> 1, pw = p & 1;
  int t = ks >> 2, u = (ks >> 1) & 1;
  int kh = 3 - ph - 2 * t, kw = 3 - pw - 2 * u;
  int oc = nt * 16 + ocl;
  union { uint4 u4; unsigned short h[8]; } Y;
#pragma unroll
  for (int i = 0; i < 8; ++i) {
    int ci = (ks & 1) * 32 + lg * 8 + i;
    Y.h[i] = f2bf(w5[(((size_t)ci * 32 + oc) * 4 + kh) * 4 + kw]);
  }
  wf[idx] = Y.u4;
}

// ---------------- correlation sampling -> f2s NHWC bf16 ----------------
__global__ __launch_bounds__(256)
void sample_k(const float* __restrict__ f2t, const float* __restrict__ coords,
              bf16* __restrict__ f2s) {
  int wv = blockIdx.x * 4 + (threadIdx.x >> 6);
  int lane = threadIdx.x & 63;
  int p0 = wv * 32;
  for (int k = 0; k < 32; ++k) {
    int P = p0 + k;
    int hw = P % HW; int n = P / HW;
    int b = n / DD, d = n % DD;
    float gx = coords[(size_t)b * 2 * HW + hw] + (float)(d / 7 - 3);
    float gy = coords[((size_t)b * 2 + 1) * HW + hw] + (float)(d % 7 - 3);
    float x0f = floorf(gx), y0f = floorf(gy);
    float wx = gx - x0f, wy = gy - y0f;
    int x0 = (int)x0f, y0 = (int)y0f;
    const float* base = f2t + (size_t)b * HW * 128;
    float r0 = 0.f, r1 = 0.f;
#pragma unroll
    for (int c = 0; c < 4; ++c) {
      int xi = x0 + (c & 1), yi = y0 + (c >> 1);
      float wgt = ((c & 1) ? wx : 1.f - wx) * ((c >> 1) ? wy : 1.f - wy);
      if (xi < 0 || xi >= Ww || yi < 0 || yi >= Hh) wgt = 0.f;
      int xc = min(max(xi, 0), Ww - 1), yc = min(max(yi, 0), Hh - 1);
      const float* pv = base + ((size_t)(yc * Ww + xc)) * 128 + 2 * lane;
      r0 += wgt * pv[0];
      r1 += wgt * pv[1];
    }
    unsigned pack = (unsigned)f2bf(r0) | ((unsigned)f2bf(r1) << 16);
    ((unsigned*)f2s)[(size_t)P * 64 + lane] = pack;
  }
}

// ---------------- 32x32x16 MFMA conv (stride 1, CIN=128) ----------------
// Weights read directly from global (L2-resident, frag-ordered); only the
// input tile is staged in LDS. 2 barriers per cih slice.
template<int COUT, int NT, int MT, int NB, int GR, int GC, bool OUTF32, bool HAS_BASE,
         bool HAS_BN, bool HAS_STATS>
__global__ __launch_bounds__(((GR * GC) / MT) * (NT / NB) * 64)
void conv32_k(const bf16* __restrict__ in, const uint4* __restrict__ wf,
              void* __restrict__ outv, const float* __restrict__ base,
              const float* __restrict__ bn_a, const float* __restrict__ bn_b,
              float* __restrict__ stats,
              int N, int H, int W, int DIV) {
  constexpr int NW = ((GR * GC) / MT) * (NT / NB);
  constexpr int BR = GR * 2, BC = GC * 16;
  constexpr int IR = BR + 2, IC = BC + 2;
  constexpr int INB = IR * IC * 128;
  __shared__ __align__(16) char lds[INB];

  const int tid = threadIdx.x;
  const int lane = tid & 63;
  const int wv = tid >> 6;
  const int lm = lane & 31, lh = lane >> 5;
  const int dh = lm >> 4, dw = lm & 15;
  constexpr int NG = NT / NB;
  const int mg = wv / NG, ng = wv % NG;

  const int tW = W / BC, tH = H / BR;
  const int tile = blockIdx.x % (tH * tW);
  const int n = blockIdx.x / (tH * tW);
  const int oh0 = (tile / tW) * BR, ow0 = (tile % tW) * BC;
  const size_t inbase = (size_t)n * H * W * 128;

  int trA[MT], tcA[MT];
#pragma unroll
  for (int i = 0; i < MT; ++i) { int mt = mg * MT + i; trA[i] = mt / GC; tcA[i] = mt % GC; }

  f16v acc[MT][NB];
#pragma unroll
  for (int i = 0; i < MT; ++i)
#pragma unroll
    for (int j = 0; j < NB; ++j)
#pragma unroll
      for (int r = 0; r < 16; ++r) acc[i][j][r] = 0.f;

  for (int cih = 0; cih < 2; ++cih) {
    __syncthreads();
    for (int idx = tid; idx < IR * IC * 8; idx += NW * 64) {
      int h8 = idx & 7;
      int icl = (idx >> 3) % IC;
      int ihl = (idx >> 3) / IC;
      int ih = oh0 - 1 + ihl, iw = ow0 - 1 + icl;
      uint4 v = make_uint4(0u, 0u, 0u, 0u);
      if (ih >= 0 && ih < H && iw >= 0 && iw < W) {
        v = *(const uint4*)(in + inbase + ((size_t)(ih * W + iw)) * 128 + cih * 64 + h8 * 8);
        v = bn8<HAS_BN>(v, bn_a, bn_b, cih * 64 + h8 * 8);
      }
      int bbyte = (ihl * IC + icl) * 128 + h8 * 16;
      bbyte ^= (icl & 7) << 4;
      *(uint4*)(lds + bbyte) = v;
    }
    __syncthreads();

    for (int khw = 0; khw < 9; ++khw) {
      const int kh = khw / 3, kw = khw % 3;
      const uint4* wfp = wf + (size_t)(khw * 2 + cih) * (NT * 256);
#pragma unroll
      for (int ks = 0; ks < 4; ++ks) {
        s8v Af[MT], Bf[NB];
#pragma unroll
        for (int i = 0; i < MT; ++i) {
          int rl = trA[i] * 2 + dh + kh;
          int cl = tcA[i] * 16 + dw + kw;
          int bbyte = (rl * IC + cl) * 128 + ks * 32 + lh * 16;
          bbyte ^= (cl & 7) << 4;
          Af[i] = *(const s8v*)(lds + bbyte);
        }
#pragma unroll
        for (int j = 0; j < NB; ++j)
          Bf[j] = as_s8v(wfp[(ks * NT + ng * NB + j) * 64 + lh * 32 + lm]);
#pragma unroll
        for (int i = 0; i < MT; ++i)
#pragma unroll
          for (int j = 0; j < NB; ++j)
            acc[i][j] = __builtin_amdgcn_mfma_f32_32x32x16_bf16(Af[i], Bf[j], acc[i][j], 0, 0, 0);
      }
    }
  }

  const size_t obase = (size_t)n * H * W * COUT;
  const float* bptr = nullptr;
  if constexpr (HAS_BASE) bptr = base + (size_t)(n / DIV) * H * W * COUT;

  float sacc[NB], qacc[NB];
#pragma unroll
  for (int j = 0; j < NB; ++j) { sacc[j] = 0.f; qacc[j] = 0.f; }

#pragma unroll
  for (int i = 0; i < MT; ++i) {
#pragma unroll
    for (int j = 0; j < NB; ++j) {
      int oc = (ng * NB + j) * 32 + lm;
#pragma unroll
      for (int r = 0; r < 16; ++r) {
        int row = (r & 3) + 8 * (r >> 2) + 4 * lh;
        int oh = oh0 + trA[i] * 2 + (row >> 4);
        int ow = ow0 + tcA[i] * 16 + (row & 15);
        size_t pix = (size_t)(oh * W + ow);
        float v = acc[i][j][r];
        if constexpr (HAS_BASE) v += bptr[pix * COUT + oc];
        if constexpr (HAS_STATS) { sacc[j] += v; qacc[j] += v * v; }
        if constexpr (OUTF32) ((float*)outv)[obase + pix * COUT + oc] = v;
        else ((bf16*)outv)[obase + pix * COUT + oc] = __float2bfloat16(v);
      }
    }
  }

  if constexpr (HAS_STATS) {
    __shared__ float sred[2 * COUT];
    for (int i = tid; i < 2 * COUT; i += NW * 64) sred[i] = 0.f;
    __syncthreads();
#pragma unroll
    for (int j = 0; j < NB; ++j) {
      int oc = (ng * NB + j) * 32 + lm;
      atomicAdd(&sred[oc], sacc[j]);
      atomicAdd(&sred[COUT + oc], qacc[j]);
    }
    __syncthreads();
    for (int i = tid; i < 2 * COUT; i += NW * 64) atomicAdd(&stats[i], sred[i]);
  }
}

// ---------------- 16x16x32 MFMA conv (stride 1 or 2) ----------------
template<int COUT, int NT, int MT, int NB, int GR, int GC, int STRIDE,
         int CINT, int CPS, int NSTAGE, int KPS, bool HAS_BN, bool HAS_STATS>
__global__ __launch_bounds__(((GR * GC) / MT) * (NT / NB) * 64)
void conv16_k(const bf16* __restrict__ in, const uint4* __restrict__ wf,
              bf16* __restrict__ out, const float* __restrict__ bn_a,
              const float* __restrict__ bn_b, float* __restrict__ stats,
              int N, int HO, int WO, int HI, int WI) {
  constexpr int NW = ((GR * GC) / MT) * (NT / NB);
  constexpr int BR = GR, BC = GC * 16;
  constexpr int IR = STRIDE * (BR - 1) + 3;
  constexpr int IC = STRIDE * (BC - 1) + 3 + (STRIDE == 2 ? 1 : 0);
  constexpr int ROWB = CPS * 2;
  constexpr int SLOTM = ROWB / 16 - 1;
  constexpr int INB = IR * IC * ROWB;
  __shared__ __align__(16) char lds[INB];

  const int tid = threadIdx.x;
  const int lane = tid & 63;
  const int wv = tid >> 6;
  const int lm = lane & 15, lg = lane >> 4;
  constexpr int NG = NT / NB;
  const int mg = wv / NG, ng = wv % NG;

  const int tW = WO / BC, tH = HO / BR;
  const int tile = blockIdx.x % (tH * tW);
  const int n = blockIdx.x / (tH * tW);
  const int oh0 = (tile / tW) * BR, ow0 = (tile % tW) * BC;
  const int ih0 = STRIDE * oh0 - 1, iw0 = STRIDE * ow0 - 1;
  const size_t inbase = (size_t)n * HI * WI * CINT;

  int trA[MT], tcA[MT];
#pragma unroll
  for (int i = 0; i < MT; ++i) { int mt = mg * MT + i; trA[i] = mt / GC; tcA[i] = mt % GC; }

  f4v acc[MT][NB];
#pragma unroll
  for (int i = 0; i < MT; ++i)
#pragma unroll
    for (int j = 0; j < NB; ++j)
#pragma unroll
      for (int r = 0; r < 4; ++r) acc[i][j][r] = 0.f;

  for (int st = 0; st < NSTAGE; ++st) {
    __syncthreads();
    for (int idx = tid; idx < IR * IC * (CPS / 8); idx += NW * 64) {
      int h8 = idx % (CPS / 8);
      int rest = idx / (CPS / 8);
      int icl = rest % IC;
      int ihl = rest / IC;
      int ih = ih0 + ihl, iw = iw0 + icl;
      uint4 v = make_uint4(0u, 0u, 0u, 0u);
      if (ih >= 0 && ih < HI && iw >= 0 && iw < WI) {
        v = *(const uint4*)(in + inbase + ((size_t)(ih * WI + iw)) * CINT + st * CPS + h8 * 8);
        v = bn8<HAS_BN>(v, bn_a, bn_b, st * CPS + h8 * 8);
      }
      int bbyte = (ihl * IC + icl) * ROWB + h8 * 16;
      bbyte ^= ((icl >> (STRIDE - 1)) & SLOTM) << 4;
      *(uint4*)(lds + bbyte) = v;
    }
    __syncthreads();

    for (int khw = 0; khw < 9; ++khw) {
      const int kh = khw / 3, kw = khw % 3;
      const uint4* wfp = wf + (size_t)(khw * NSTAGE + st) * (KPS * NT * 64);
#pragma unroll
      for (int ks = 0; ks < KPS; ++ks) {
        s8v Af[MT], Bf[NB];
#pragma unroll
        for (int i = 0; i < MT; ++i) {
          int rl = STRIDE * trA[i] + kh;
          int cl = STRIDE * (tcA[i] * 16 + lm) + kw;
          int bbyte = (rl * IC + cl) * ROWB + ks * 64 + lg * 16;
          bbyte ^= ((cl >> (STRIDE - 1)) & SLOTM) << 4;
          Af[i] = *(const s8v*)(lds + bbyte);
        }
#pragma unroll
        for (int j = 0; j < NB; ++j)
          Bf[j] = as_s8v(wfp[(ks * NT + ng * NB + j) * 64 + lg * 16 + lm]);
#pragma unroll
        for (int i = 0; i < MT; ++i)
#pragma unroll
          for (int j = 0; j < NB; ++j)
            acc[i][j] = __builtin_amdgcn_mfma_f32_16x16x32_bf16(Af[i], Bf[j], acc[i][j], 0, 0, 0);
      }
    }
  }

  const size_t obase = (size_t)n * HO * WO * COUT;
  float sacc[NB], qacc[NB];
#pragma unroll
  for (int j = 0; j < NB; ++j) { sacc[j] = 0.f; qacc[j] = 0.f; }

#pragma unroll
  for (int i = 0; i < MT; ++i) {
#pragma unroll
    for (int j = 0; j < NB; ++j) {
      int oc = (ng * NB + j) * 16 + lm;
#pragma unroll
      for (int r = 0; r < 4; ++r) {
        int oh = oh0 + trA[i];
        int ow = ow0 + tcA[i] * 16 + lg * 4 + r;
        float v = acc[i][j][r];
        if constexpr (HAS_STATS) { sacc[j] += v; qacc[j] += v * v; }
        out[obase + (size_t)(oh * WO + ow) * COUT + oc] = __float2bfloat16(v);
      }
    }
  }

  if constexpr (HAS_STATS) {
    __shared__ float sred[2 * COUT];
    for (int i = tid; i < 2 * COUT; i += NW * 64) sred[i] = 0.f;
    __syncthreads();
#pragma unroll
    for (int j = 0; j < NB; ++j) {
      int oc = (ng * NB + j) * 16 + lm;
      atomicAdd(&sred[oc], sacc[j]);
      atomicAdd(&sred[COUT + oc], qacc[j]);
    }
    __syncthreads();
    for (int i = tid; i < 2 * COUT; i += NW * 64) atomicAdd(&stats[i], sred[i]);
  }
}

// ---------------- deconv (ConvTranspose2d k4 s2 p1, 64->32) via 16x16x32 ----------------
__global__ __launch_bounds__(256)
void deconv16_k(const bf16* __restrict__ in, const uint4* __restrict__ wf5,
                bf16* __restrict__ out, const float* __restrict__ a4,
                const float* __restrict__ b4, float* __restrict__ stats) {
  constexpr int IR = 6, IC = 50, INB = IR * IC * 128;
  __shared__ __align__(16) char lds[INB];
  __shared__ float sred[64];
  const int tid = threadIdx.x;
  const int lane = tid & 63, wv = tid >> 6;
  const int lm = lane & 15, lg = lane >> 4;
  const int n = blockIdx.x / 6;
  const int qh0 = (blockIdx.x % 6) * 4;
  const size_t ibase = (size_t)n * HW2 * 64;

  for (int idx = tid; idx < 64; idx += 256) sred[idx] = 0.f;

  for (int idx = tid; idx < IR * IC * 8; idx += 256) {
    int h8 = idx & 7; int icl = (idx >> 3) % IC; int ihl = (idx >> 3) / IC;
    int ih = qh0 - 1 + ihl, iw = -1 + icl;
    uint4 v = make_uint4(0u, 0u, 0u, 0u);
    if (ih >= 0 && ih < H2 && iw >= 0 && iw < W2) {
      v = *(const uint4*)(in + ibase + ((size_t)(ih * W2 + iw)) * 64 + h8 * 8);
      v = bn8<true>(v, a4, b4, h8 * 8);
    }
    int bbyte = (ihl * IC + icl) * 128 + h8 * 16;
    bbyte ^= (icl & 7) << 4;
    *(uint4*)(lds + bbyte) = v;
  }
  __syncthreads();

  int trA[3], tcA[3];
#pragma unroll
  for (int i = 0; i < 3; ++i) { int mt = wv * 3 + i; trA[i] = mt / 3; tcA[i] = mt % 3; }

  float sacc[2], qacc[2];
  sacc[0] = sacc[1] = qacc[0] = qacc[1] = 0.f;

  for (int p = 0; p < 4; ++p) {
    const int ph = p >> 1, pw = p & 1;
    f4v acc[3][2];
#pragma unroll
    for (int i = 0; i < 3; ++i)
#pragma unroll
      for (int j = 0; j < 2; ++j)
#pragma unroll
        for (int r = 0; r < 4; ++r) acc[i][j][r] = 0.f;
#pragma unroll
    for (int ks = 0; ks < 8; ++ks) {
      int t = ks >> 2, u = (ks >> 1) & 1, cb = ks & 1;
      s8v Af[3], Bf[2];
#pragma unroll
      for (int i = 0; i < 3; ++i) {
        int rl = trA[i] + t + ph;
        int cl = tcA[i] * 16 + lm + u + pw;
        int bbyte = (rl * IC + cl) * 128 + cb * 64 + lg * 16;
        bbyte ^= (cl & 7) << 4;
        Af[i] = *(const s8v*)(lds + bbyte);
      }
#pragma unroll
      for (int j = 0; j < 2; ++j)
        Bf[j] = as_s8v(wf5[p * 1024 + (ks * 2 + j) * 64 + lg * 16 + lm]);
#pragma unroll
      for (int i = 0; i < 3; ++i)
#pragma unroll
        for (int j = 0; j < 2; ++j)
          acc[i][j] = __builtin_amdgcn_mfma_f32_16x16x32_bf16(Af[i], Bf[j], acc[i][j], 0, 0, 0);
    }
#pragma unroll
    for (int i = 0; i < 3; ++i) {
#pragma unroll
      for (int j = 0; j < 2; ++j) {
        int oc = j * 16 + lm;
#pragma unroll
        for (int r = 0; r < 4; ++r) {
          int qh = qh0 + trA[i];
          int qw = tcA[i] * 16 + lg * 4 + r;
          int oh = 2 * qh + ph, ow = 2 * qw + pw;
          float v = acc[i][j][r];
          sacc[j] += v; qacc[j] += v * v;
          out[((size_t)n * HW + oh * Ww + ow) * 32 + oc] = __float2bfloat16(v);
        }
      }
    }
  }

  __syncthreads();
#pragma unroll
  for (int j = 0; j < 2; ++j) {
    int oc = j * 16 + lm;
    atomicAdd(&sred[oc], sacc[j]);
    atomicAdd(&sred[32 + oc], qacc[j]);
  }
  __syncthreads();
  for (int i = tid; i < 64; i += 256) atomicAdd(&stats[i], sred[i]);
}

// ---------------- BN finalize ----------------
__global__ void bnfin_k(const float* __restrict__ sums, const float* __restrict__ gamma,
                        const float* __restrict__ beta, float* __restrict__ ab, int C, float invCnt) {
  int c = blockIdx.x * blockDim.x + threadIdx.x;
  if (c >= C) return;
  float mean = sums[c] * invCnt;
  float var = sums[C + c] * invCnt - mean * mean;
  float a = gamma[c] * rsqrtf(var + 1e-5f);
  ab[c] = a;
  ab[C + c] = beta[c] - mean * a;
}

// ---------------- conv6 (32->1, 3x3, fused bn5) ----------------
__global__ __launch_bounds__(256)
void conv6_k(const bf16* __restrict__ y5, const float* __restrict__ w6,
             const float* __restrict__ b6, const float* __restrict__ a5,
             const float* __restrict__ bb5, float* __restrict__ y6) {
  int o = blockIdx.x * 256 + threadIdx.x;
  if (o >= Nn * HW) return;
  int hw = o % HW; int n = o / HW;
  int h = hw / Ww, w = hw % Ww;
  float acc = b6[0];
  for (int kh = 0; kh < 3; ++kh) {
    int ih = h - 1 + kh; if (ih < 0 || ih >= Hh) continue;
    for (int kw = 0; kw < 3; ++kw) {
      int iw = w - 1 + kw; if (iw < 0 || iw >= Ww) continue;
      const bf16* p = y5 + ((size_t)n * HW + ih * Ww + iw) * 32;
      int khw = kh * 3 + kw;
#pragma unroll
      for (int c8 = 0; c8 < 4; ++c8) {
        union { uint4 u; unsigned short hh[8]; } X;
        X.u = *(const uint4*)(p + c8 * 8);
#pragma unroll
        for (int i = 0; i < 8; ++i) {
          int c = c8 * 8 + i;
          float f = fmaxf(bf2f(X.hh[i]) * a5[c] + bb5[c], 0.f);
          acc += f * w6[c * 9 + khw];
        }
      }
    }
  }
  y6[o] = acc;
}

// ---------------- DAP ----------------
__global__ __launch_bounds__(256)
void dap_k(const float* __restrict__ y6, const float* __restrict__ dap, float* __restrict__ out) {
  int o = blockIdx.x * 256 + threadIdx.x;
  if (o >= Bb * DD * HW) return;
  int hw = o % HW;
  int e = (o / HW) % DD;
  int b = o / (HW * DD);
  float s = 0.f;
#pragma unroll 7
  for (int d = 0; d < DD; ++d) s += dap[e * DD + d] * y6[((size_t)(b * DD + d)) * HW + hw];
  out[o] = s;
}

// ---------------- host launch ----------------
extern "C" void kernel_launch(void* const* d_in, const int* in_sizes, int n_in,
                              void* d_out, int out_size, void* d_ws, size_t ws_size,
                              hipStream_t stream) {
  const float* f1 = (const float*)d_in[0];
  const float* f2 = (const float*)d_in[1];
  const float* coords = (const float*)d_in[2];
  const float* w1 = (const float*)d_in[3];
  const float* g1 = (const float*)d_in[4];
  const float* b1 = (const float*)d_in[5];
  const float* w2 = (const float*)d_in[6];
  const float* g2 = (const float*)d_in[7];
  const float* b2 = (const float*)d_in[8];
  const float* w3 = (const float*)d_in[9];
  const float* g3 = (const float*)d_in[10];
  const float* b3 = (const float*)d_in[11];
  const float* w4 = (const float*)d_in[12];
  const float* g4 = (const float*)d_in[13];
  const float* b4 = (const float*)d_in[14];
  const float* w5 = (const float*)d_in[15];
  const float* g5 = (const float*)d_in[16];
  const float* b5 = (const float*)d_in[17];
  const float* w6 = (const float*)d_in[18];
  const float* b6 = (const float*)d_in[19];
  const float* dap = (const float*)d_in[20];
  float* out = (float*)d_out;
  char* ws = (char*)d_ws;
  if (ws_size < WS_NEEDED) return;

  uint4* wf1a = (uint4*)(ws + off_wf1a);
  uint4* wf1b = (uint4*)(ws + off_wf1b);
  uint4* wf3 = (uint4*)(ws + off_wf3);
  uint4* wf2 = (uint4*)(ws + off_wf2);
  uint4* wf4 = (uint4*)(ws + off_wf4);
  uint4* wf5 = (uint4*)(ws + off_wf5);
  bf16* f1t = (bf16*)(ws + off_f1t);
  float* y1a = (float*)(ws + off_y1a);
  float* f2t = (float*)(ws + off_f2t);
  bf16* f2s = (bf16*)(ws + off_f2s);
  bf16* y1 = (bf16*)(ws + off_y1);
  bf16* y2 = (bf16*)(ws + off_y2);
  bf16* y3 = (bf16*)(ws + off_y3);
  bf16* y4 = (bf16*)(ws + off_y4);
  bf16* y5 = (bf16*)(ws + off_y5);
  float* y6 = (float*)(ws + off_y6);
  float* st0 = (float*)(ws + off_stats) + 0 * 512;
  float* st1 = (float*)(ws + off_stats) + 1 * 512;
  float* st2 = (float*)(ws + off_stats) + 2 * 512;
  float* st3 = (float*)(ws + off_stats) + 3 * 512;
  float* st4 = (float*)(ws + off_stats) + 4 * 512;

  zero_k<<<10, 256, 0, stream>>>((float*)(ws + off_stats), 2560);

  tr_f2_k<<<576, 256, 0, stream>>>(f2, f2t);
  tr_f1_k<<<576, 256, 0, stream>>>(f1, f1t);
  prep32_k<<<54, 256, 0, stream>>>(w1, wf1a, 3, 256, 0);
  prep32_k<<<54, 256, 0, stream>>>(w1, wf1b, 3, 256, 128);
  prep32_k<<<72, 256, 0, stream>>>(w3, wf3, 4, 128, 0);
  prep16_k<<<54, 256, 0, stream>>>(w2, wf2, 8, 96, 3, 32, 1);
  prep16_k<<<36, 256, 0, stream>>>(w4, wf4, 4, 128, 2, 64, 2);
  prep_w5_k<<<16, 256, 0, stream>>>(w5, wf5);

  sample_k<<<3528, 256, 0, stream>>>(f2t, coords, f2s);

  // conv1 f1-half (shared across 49 displacements), f32 NHWC out
  conv32_k<96, 3, 2, 3, 4, 2, true, false, false, false><<<36, 256, 0, stream>>>(
      f1t, wf1a, y1a, nullptr, nullptr, nullptr, nullptr, 2, Hh, Ww, 1);
  // conv1 f2-half + base, fused BN1 stats
  conv32_k<96, 3, 2, 3, 4, 2, false, true, false, true><<<1764, 256, 0, stream>>>(
      f2s, wf1b, y1, y1a, nullptr, nullptr, st0, Nn, Hh, Ww, DD);
  bnfin_k<<<1, 256, 0, stream>>>(st0, g1, b1, st0 + 256, 96, 1.f / (98.f * 4608.f));

  // conv2 stride 2 (bn1 fused on input staging), fused BN2 stats
  conv16_k<128, 8, 3, 4, 2, 3, 2, 96, 32, 3, 1, true, true><<<1176, 256, 0, stream>>>(
      y1, wf2, y2, st0 + 256, st0 + 256 + 96, st1, Nn, H2, W2, Hh, Ww);
  bnfin_k<<<1, 256, 0, stream>>>(st1, g2, b2, st1 + 256, 128, 1.f / (98.f * 1152.f));

  // conv3 (bn2 fused), fused BN3 stats
  conv32_k<128, 4, 3, 2, 2, 3, false, false, true, true><<<588, 256, 0, stream>>>(
      y2, wf3, y3, nullptr, st1 + 256, st1 + 256 + 128, st2, Nn, H2, W2, 1);
  bnfin_k<<<1, 256, 0, stream>>>(st2, g3, b3, st2 + 256, 128, 1.f / (98.f * 1152.f));

  // conv4 (bn3 fused), fused BN4 stats
  conv16_k<64, 4, 3, 4, 4, 3, 1, 128, 64, 2, 2, true, true><<<588, 256, 0, stream>>>(
      y3, wf4, y4, st2 + 256, st2 + 256 + 128, st3, Nn, H2, W2, H2, W2);
  bnfin_k<<<1, 256, 0, stream>>>(st3, g4, b4, st3 + 256, 64, 1.f / (98.f * 1152.f));

  // deconv (bn4 fused), fused BN5 stats
  deconv16_k<<<588, 256, 0, stream>>>(y4, wf5, y5, st3 + 256, st3 + 256 + 64, st4);
  bnfin_k<<<1, 256, 0, stream>>>(st4, g5, b5, st4 + 256, 32, 1.f / (98.f * 4608.f));

  // conv6 (bn5 fused) + bias -> f32
  conv6_k<<<1764, 256, 0, stream>>>(y5, w6, b6, st4 + 256, st4 + 256 + 32, y6);

  // DAP
  dap_k<<<1764, 256, 0, stream>>>(y6, dap, out);
}

// Round 5
// 686.523 us; speedup vs baseline: 8.3403x; 1.1174x over previous
//
#include <hip/hip_runtime.h>
#include <hip/hip_bf16.h>

using bf16 = __hip_bfloat16;
typedef __attribute__((ext_vector_type(8))) short s8v;
typedef __attribute__((ext_vector_type(4))) float f4v;
typedef __attribute__((ext_vector_type(16))) float f16v;

static constexpr int Bb = 2, Hh = 48, Ww = 96;
static constexpr int HW = Hh * Ww;              // 4608
static constexpr int DD = 49, Nn = Bb * DD;     // 98
static constexpr int H2 = 24, W2 = 48, HW2 = H2 * W2;

// ---------------- workspace layout (bytes) ----------------
static constexpr size_t off_wf1a = 0;                 // 221184
static constexpr size_t off_wf1b = 221184;            // 221184
static constexpr size_t off_wf3  = 442368;            // 294912
static constexpr size_t off_wf2  = 737280;            // 221184
static constexpr size_t off_wf4  = 958464;            // 147456
static constexpr size_t off_wf5  = 1105920;           // 65536
static constexpr size_t off_f1t  = 1171456;           // bf16 [2][4608][128] = 2359296
static constexpr size_t off_y1a  = 3530752;           // f32  [2][4608][96]  = 3538944
static constexpr size_t off_stats= 7069696;           // 5*2048
static constexpr size_t off_f2s  = 7079936;           // bf16 [98][4608][128] = 115605504
static constexpr size_t off_y1   = 122685440;         // bf16 [98][4608][96] = 86704128
static constexpr size_t off_f2t  = off_y1;            // f32 [2][4608][128] (dead before y1 written)
static constexpr size_t off_y2   = off_f2s;                   // bf16 [98][1152][128]
static constexpr size_t off_y3   = off_f2s + 28901376;        // bf16 [98][1152][128]
static constexpr size_t off_y4   = off_f2s + 57802752;        // bf16 [98][1152][64]
static constexpr size_t off_y5   = off_f2s + 72253440;        // bf16 [98][4608][32]
static constexpr size_t off_y6   = off_f2s + 101154816;       // f32 [98][4608]
static constexpr size_t WS_NEEDED = 209389568;

// ---------------- helpers ----------------
__device__ __forceinline__ float bf2f(unsigned short h) {
  return __uint_as_float(((unsigned)h) << 16);
}
__device__ __forceinline__ unsigned short f2bf(float f) {
  __hip_bfloat16 h = __float2bfloat16(f);
  union { __hip_bfloat16 x; unsigned short u; } cv; cv.x = h; return cv.u;
}
template<bool EN>
__device__ __forceinline__ uint4 bn8(uint4 v, const float* a, const float* b, int c0) {
  if constexpr (!EN) return v;
  union { uint4 u; unsigned short h[8]; } X; X.u = v;
#pragma unroll
  for (int i = 0; i < 8; ++i) {
    float f = fmaxf(bf2f(X.h[i]) * a[c0 + i] + b[c0 + i], 0.f);
    X.h[i] = f2bf(f);
  }
  return X.u;
}
__device__ __forceinline__ s8v as_s8v(uint4 v) {
  union { uint4 u; s8v s; } cv; cv.u = v; return cv.s;
}
__device__ __forceinline__ int swz(int icl) { return ((icl >> 1) ^ (icl >> 3)) & 3; }

// ---------------- small utility kernels ----------------
__global__ __launch_bounds__(256) void zero_k(float* __restrict__ p, int n) {
  int i = blockIdx.x * 256 + threadIdx.x;
  if (i < n) p[i] = 0.f;
}

// f2 [2][128][4608] f32 -> f2t [2][4608][128] f32
__global__ __launch_bounds__(256) void tr_f2_k(const float* __restrict__ f2, float* __restrict__ f2t) {
  int o = blockIdx.x * 256 + threadIdx.x;
  if (o >= 2 * HW * 16) return;
  int c8 = o & 15; int pos = (o >> 4) % HW; int b = o / (HW * 16);
  float v[8];
#pragma unroll
  for (int i = 0; i < 8; ++i) v[i] = f2[((size_t)(b * 128 + c8 * 8 + i)) * HW + pos];
  float* dst = f2t + ((size_t)b * HW + pos) * 128 + c8 * 8;
#pragma unroll
  for (int i = 0; i < 8; ++i) dst[i] = v[i];
}

// f1 [2][128][4608] f32 -> f1t [2][4608][128] bf16
__global__ __launch_bounds__(256) void tr_f1_k(const float* __restrict__ f1, bf16* __restrict__ f1t) {
  int o = blockIdx.x * 256 + threadIdx.x;
  if (o >= 2 * HW * 16) return;
  int c8 = o & 15; int pos = (o >> 4) % HW; int b = o / (HW * 16);
  union { uint4 u; unsigned short h[8]; } Y;
#pragma unroll
  for (int i = 0; i < 8; ++i) Y.h[i] = f2bf(f1[((size_t)(b * 128 + c8 * 8 + i)) * HW + pos]);
  *(uint4*)(f1t + ((size_t)b * HW + pos) * 128 + c8 * 8) = Y.u;
}

// weight prep: frag-ordered for 32x32x16 path.  [khw][cih][ks][nt][lh][ocl]x8bf16
__global__ __launch_bounds__(256)
void prep32_k(const float* __restrict__ w, uint4* __restrict__ wf, int NT, int CINT, int ciOff) {
  int idx = blockIdx.x * 256 + threadIdx.x;
  int total = 9 * 2 * 4 * NT * 64;
  if (idx >= total) return;
  int ocl = idx & 31; int lh = (idx >> 5) & 1;
  int q = idx >> 6; int nt = q % NT; int rest = q / NT;
  int ks = rest & 3; int cih = (rest >> 2) & 1; int khw = rest >> 3;
  int oc = nt * 32 + ocl;
  union { uint4 u; unsigned short h[8]; } Y;
#pragma unroll
  for (int i = 0; i < 8; ++i) {
    int ci = ciOff + cih * 64 + ks * 16 + lh * 8 + i;
    Y.h[i] = f2bf(w[((size_t)oc * CINT + ci) * 9 + khw]);
  }
  wf[idx] = Y.u;
}

// frag-ordered for 16x16x32 path.  [khw][st][ks][nt][lg][ocl]x8bf16
__global__ __launch_bounds__(256)
void prep16_k(const float* __restrict__ w, uint4* __restrict__ wf, int NT, int CINT,
              int NSTAGE, int CPS, int KPS) {
  int idx = blockIdx.x * 256 + threadIdx.x;
  int total = 9 * NSTAGE * KPS * NT * 64;
  if (idx >= total) return;
  int ocl = idx & 15; int lg = (idx >> 4) & 3;
  int q = idx >> 6; int nt = q % NT; int q2 = q / NT;
  int ks = q2 % KPS; int q3 = q2 / KPS;
  int st = q3 % NSTAGE; int khw = q3 / NSTAGE;
  int oc = nt * 16 + ocl;
  union { uint4 u; unsigned short h[8]; } Y;
#pragma unroll
  for (int i = 0; i < 8; ++i) {
    int ci = st * CPS + ks * 32 + lg * 8 + i;
    Y.h[i] = f2bf(w[((size_t)oc * CINT + ci) * 9 + khw]);
  }
  wf[idx] = Y.u;
}

// w5 [64ci][32oc][4][4] -> frag-ordered [p][ks][nt][lg][ocl]x8
__global__ __launch_bounds__(256)
void prep_w5_k(const float* __restrict__ w5, uint4* __restrict__ wf) {
  int idx = blockIdx.x * 256 + threadIdx.x;
  if (idx >= 4096) return;
  int ocl = idx & 15; int lg = (idx >> 4) & 3;
  int nt = (idx >> 6) & 1; int ks = (idx >> 7) & 7; int p = idx >> 10;
  int ph = p >> 1, pw = p & 1;
  int t = ks >> 2, u = (ks >> 1) & 1;
  int kh = 3 - ph - 2 * t, kw = 3 - pw - 2 * u;
  int oc = nt * 16 + ocl;
  union { uint4 u4; unsigned short h[8]; } Y;
#pragma unroll
  for (int i = 0; i < 8; ++i) {
    int ci = (ks & 1) * 32 + lg * 8 + i;
    Y.h[i] = f2bf(w5[(((size_t)ci * 32 + oc) * 4 + kh) * 4 + kw]);
  }
  wf[idx] = Y.u4;
}

// ---------------- correlation sampling -> f2s NHWC bf16 ----------------
__global__ __launch_bounds__(256)
void sample_k(const float* __restrict__ f2t, const float* __restrict__ coords,
              bf16* __restrict__ f2s) {
  int wv = blockIdx.x * 4 + (threadIdx.x >> 6);
  int lane = threadIdx.x & 63;
  int p0 = wv * 32;
  for (int k = 0; k < 32; ++k) {
    int P = p0 + k;
    int hw = P % HW; int n = P / HW;
    int b = n / DD, d = n % DD;
    float gx = coords[(size_t)b * 2 * HW + hw] + (float)(d / 7 - 3);
    float gy = coords[((size_t)b * 2 + 1) * HW + hw] + (float)(d % 7 - 3);
    float x0f = floorf(gx), y0f = floorf(gy);
    float wx = gx - x0f, wy = gy - y0f;
    int x0 = (int)x0f, y0 = (int)y0f;
    const float* base = f2t + (size_t)b * HW * 128;
    float r0 = 0.f, r1 = 0.f;
#pragma unroll
    for (int c = 0; c < 4; ++c) {
      int xi = x0 + (c & 1), yi = y0 + (c >> 1);
      float wgt = ((c & 1) ? wx : 1.f - wx) * ((c >> 1) ? wy : 1.f - wy);
      if (xi < 0 || xi >= Ww || yi < 0 || yi >= Hh) wgt = 0.f;
      int xc = min(max(xi, 0), Ww - 1), yc = min(max(yi, 0), Hh - 1);
      const float* pv = base + ((size_t)(yc * Ww + xc)) * 128 + 2 * lane;
      r0 += wgt * pv[0];
      r1 += wgt * pv[1];
    }
    unsigned pack = (unsigned)f2bf(r0) | ((unsigned)f2bf(r1) << 16);
    ((unsigned*)f2s)[(size_t)P * 64 + lane] = pack;
  }
}

// ---------------- staging helpers (32ch slices, reg-staged) ----------------
template<int NLD, int NTHR, int NGRAN, int IC, int CIN>
__device__ __forceinline__ void stage_issue(const bf16* __restrict__ in, size_t inbase,
    int ih0, int iw0, int HI, int WI, int ksl, int tid, uint4 (&stg)[NLD]) {
#pragma unroll
  for (int t = 0; t < NLD; ++t) {
    int idx = tid + t * NTHR;
    uint4 v = make_uint4(0u, 0u, 0u, 0u);
    if (idx < NGRAN) {
      int h8 = idx & 3; int pix = idx >> 2;
      int icl = pix % IC, ihl = pix / IC;
      int ih = ih0 + ihl, iw = iw0 + icl;
      if (ih >= 0 && ih < HI && iw >= 0 && iw < WI)
        v = *(const uint4*)(in + inbase + ((size_t)(ih * WI + iw)) * CIN + ksl * 32 + h8 * 8);
    }
    stg[t] = v;
  }
}

template<int NLD, int NTHR, int NGRAN, int IC, int ROWB, bool HAS_BN>
__device__ __forceinline__ void stage_commit(char* __restrict__ lds,
    const float* __restrict__ a, const float* __restrict__ b,
    int ih0, int iw0, int HI, int WI, int ksl, int tid, uint4 (&stg)[NLD]) {
#pragma unroll
  for (int t = 0; t < NLD; ++t) {
    int idx = tid + t * NTHR;
    if (idx < NGRAN) {
      int h8 = idx & 3; int pix = idx >> 2;
      int icl = pix % IC, ihl = pix / IC;
      uint4 v = stg[t];
      if constexpr (HAS_BN) {
        int ih = ih0 + ihl, iw = iw0 + icl;
        if (ih >= 0 && ih < HI && iw >= 0 && iw < WI) v = bn8<true>(v, a, b, ksl * 32 + h8 * 8);
      }
      int g = h8 ^ swz(icl);
      *(uint4*)(lds + (ihl * IC + icl) * ROWB + g * 16) = v;
    }
  }
}

// ---------------- 32x32x16 MFMA conv (stride 1) ----------------
// 32-ch K-slices; single LDS buffer; T14 split: next-slice loads issue before
// current compute; fully unrolled 108-MFMA compute region per slice; weights
// direct from global (L2-resident).
template<int COUT, int NT, int MT, int NB, int GR, int GC, int CIN,
         bool OUTF32, bool HAS_BASE, bool HAS_BN, bool HAS_STATS>
__global__ __launch_bounds__(((GR * GC) / MT) * (NT / NB) * 64)
void conv32_k(const bf16* __restrict__ in, const uint4* __restrict__ wf,
              void* __restrict__ outv, const float* __restrict__ base,
              const float* __restrict__ bn_a, const float* __restrict__ bn_b,
              float* __restrict__ stats, int N, int H, int W, int DIV) {
  constexpr int NW = ((GR * GC) / MT) * (NT / NB);
  constexpr int NTHR = NW * 64;
  constexpr int BR = GR * 2, BC = GC * 16;
  constexpr int IR = BR + 2, IC = BC + 2;
  constexpr int NSL = CIN / 32;
  constexpr int NGRAN = IR * IC * 4;
  constexpr int NLD = (NGRAN + NTHR - 1) / NTHR;
  __shared__ __align__(16) char lds[IR * IC * 64];

  const int tid = threadIdx.x;
  const int lane = tid & 63;
  const int wv = tid >> 6;
  const int lm = lane & 31, lh = lane >> 5;
  const int dh = lm >> 4, dw = lm & 15;
  constexpr int NG = NT / NB;
  const int mg = wv / NG, ng = wv % NG;

  const int tW = W / BC, tH = H / BR;
  const int tile = blockIdx.x % (tH * tW);
  const int n = blockIdx.x / (tH * tW);
  const int oh0 = (tile / tW) * BR, ow0 = (tile % tW) * BC;
  const int ih0 = oh0 - 1, iw0 = ow0 - 1;
  const size_t inbase = (size_t)n * H * W * CIN;

  int trA[MT], tcA[MT];
#pragma unroll
  for (int i = 0; i < MT; ++i) { int mt = mg * MT + i; trA[i] = mt / GC; tcA[i] = mt % GC; }

  f16v acc[MT][NB];
#pragma unroll
  for (int i = 0; i < MT; ++i)
#pragma unroll
    for (int j = 0; j < NB; ++j)
#pragma unroll
      for (int r = 0; r < 16; ++r) acc[i][j][r] = 0.f;

  {
    uint4 stg0[NLD];
    stage_issue<NLD, NTHR, NGRAN, IC, CIN>(in, inbase, ih0, iw0, H, W, 0, tid, stg0);
    stage_commit<NLD, NTHR, NGRAN, IC, 64, HAS_BN>(lds, bn_a, bn_b, ih0, iw0, H, W, 0, tid, stg0);
  }
  __syncthreads();

#pragma unroll
  for (int ksl = 0; ksl < NSL; ++ksl) {
    uint4 stgN[NLD];
    if (ksl + 1 < NSL)
      stage_issue<NLD, NTHR, NGRAN, IC, CIN>(in, inbase, ih0, iw0, H, W, ksl + 1, tid, stgN);

#pragma unroll
    for (int khw = 0; khw < 9; ++khw) {
      const int kh = khw / 3, kw = khw % 3;
      const uint4* wfp = wf + (size_t)(khw * 2 + (ksl >> 1)) * (NT * 256);
#pragma unroll
      for (int ks = 0; ks < 2; ++ks) {
        s8v Af[MT], Bf[NB];
#pragma unroll
        for (int i = 0; i < MT; ++i) {
          int rl = trA[i] * 2 + dh + kh;
          int cl = tcA[i] * 16 + dw + kw;
          int g = (ks * 2 + lh) ^ swz(cl);
          Af[i] = *(const s8v*)(lds + (rl * IC + cl) * 64 + g * 16);
        }
        int ks4 = (ksl & 1) * 2 + ks;
#pragma unroll
        for (int j = 0; j < NB; ++j)
          Bf[j] = as_s8v(wfp[(ks4 * NT + ng * NB + j) * 64 + lane]);
#pragma unroll
        for (int i = 0; i < MT; ++i)
#pragma unroll
          for (int j = 0; j < NB; ++j)
            acc[i][j] = __builtin_amdgcn_mfma_f32_32x32x16_bf16(Af[i], Bf[j], acc[i][j], 0, 0, 0);
      }
    }

    if (ksl + 1 < NSL) {
      __syncthreads();
      stage_commit<NLD, NTHR, NGRAN, IC, 64, HAS_BN>(lds, bn_a, bn_b, ih0, iw0, H, W, ksl + 1, tid, stgN);
      __syncthreads();
    }
  }

  const size_t obase = (size_t)n * H * W * COUT;
  const float* bptr = nullptr;
  if constexpr (HAS_BASE) bptr = base + (size_t)(n / DIV) * H * W * COUT;

  float sacc[NB], qacc[NB];
#pragma unroll
  for (int j = 0; j < NB; ++j) { sacc[j] = 0.f; qacc[j] = 0.f; }

#pragma unroll
  for (int i = 0; i < MT; ++i) {
#pragma unroll
    for (int j = 0; j < NB; ++j) {
      int oc = (ng * NB + j) * 32 + lm;
#pragma unroll
      for (int r = 0; r < 16; ++r) {
        int row = (r & 3) + 8 * (r >> 2) + 4 * lh;
        int oh = oh0 + trA[i] * 2 + (row >> 4);
        int ow = ow0 + tcA[i] * 16 + (row & 15);
        size_t pix = (size_t)(oh * W + ow);
        float v = acc[i][j][r];
        if constexpr (HAS_BASE) v += bptr[pix * COUT + oc];
        if constexpr (HAS_STATS) { sacc[j] += v; qacc[j] += v * v; }
        if constexpr (OUTF32) ((float*)outv)[obase + pix * COUT + oc] = v;
        else ((bf16*)outv)[obase + pix * COUT + oc] = __float2bfloat16(v);
      }
    }
  }

  if constexpr (HAS_STATS) {
    __shared__ float sred[2 * COUT];
    for (int i = tid; i < 2 * COUT; i += NTHR) sred[i] = 0.f;
    __syncthreads();
#pragma unroll
    for (int j = 0; j < NB; ++j) {
      int oc = (ng * NB + j) * 32 + lm;
      atomicAdd(&sred[oc], sacc[j]);
      atomicAdd(&sred[COUT + oc], qacc[j]);
    }
    __syncthreads();
    for (int i = tid; i < 2 * COUT; i += NTHR) atomicAdd(&stats[i], sred[i]);
  }
}

// ---------------- 16x16x32 MFMA conv (stride 1 or 2), 32-ch slices ----------------
template<int COUT, int NT, int MT, int NB, int GR, int GC, int STRIDE,
         int CINT, bool HAS_BN, bool HAS_STATS>
__global__ __launch_bounds__(((GR * GC) / MT) * (NT / NB) * 64)
void conv16_k(const bf16* __restrict__ in, const uint4* __restrict__ wf,
              bf16* __restrict__ out, const float* __restrict__ bn_a,
              const float* __restrict__ bn_b, float* __restrict__ stats,
              int N, int HO, int WO, int HI, int WI) {
  constexpr int NW = ((GR * GC) / MT) * (NT / NB);
  constexpr int NTHR = NW * 64;
  constexpr int BR = GR, BC = GC * 16;
  constexpr int IR = STRIDE * (BR - 1) + 3;
  constexpr int IC = STRIDE * (BC - 1) + 3 + (STRIDE == 2 ? 1 : 0);
  constexpr int ROWB = (STRIDE == 2) ? 80 : 64;   // 80B rows break stride-2 bank parity
  constexpr int NSL = CINT / 32;
  constexpr int NGRAN = IR * IC * 4;
  constexpr int NLD = (NGRAN + NTHR - 1) / NTHR;
  __shared__ __align__(16) char lds[IR * IC * ROWB];

  const int tid = threadIdx.x;
  const int lane = tid & 63;
  const int wv = tid >> 6;
  const int lm = lane & 15, lg = lane >> 4;
  constexpr int NG = NT / NB;
  const int mg = wv / NG, ng = wv % NG;

  const int tW = WO / BC, tH = HO / BR;
  const int tile = blockIdx.x % (tH * tW);
  const int n = blockIdx.x / (tH * tW);
  const int oh0 = (tile / tW) * BR, ow0 = (tile % tW) * BC;
  const int ih0 = STRIDE * oh0 - 1, iw0 = STRIDE * ow0 - 1;
  const size_t inbase = (size_t)n * HI * WI * CINT;

  int trA[MT], tcA[MT];
#pragma unroll
  for (int i = 0; i < MT; ++i) { int mt = mg * MT + i; trA[i] = mt / GC; tcA[i] = mt % GC; }

  f4v acc[MT][NB];
#pragma unroll
  for (int i = 0; i < MT; ++i)
#pragma unroll
    for (int j = 0; j < NB; ++j)
#pragma unroll
      for (int r = 0; r < 4; ++r) acc[i][j][r] = 0.f;

  {
    uint4 stg0[NLD];
    stage_issue<NLD, NTHR, NGRAN, IC, CINT>(in, inbase, ih0, iw0, HI, WI, 0, tid, stg0);
    stage_commit<NLD, NTHR, NGRAN, IC, ROWB, HAS_BN>(lds, bn_a, bn_b, ih0, iw0, HI, WI, 0, tid, stg0);
  }
  __syncthreads();

#pragma unroll
  for (int ksl = 0; ksl < NSL; ++ksl) {
    uint4 stgN[NLD];
    if (ksl + 1 < NSL)
      stage_issue<NLD, NTHR, NGRAN, IC, CINT>(in, inbase, ih0, iw0, HI, WI, ksl + 1, tid, stgN);

#pragma unroll
    for (int khw = 0; khw < 9; ++khw) {
      const int kh = khw / 3, kw = khw % 3;
      const uint4* wfp = wf + (size_t)(khw * NSL + ksl) * (NT * 64);
      s8v Af[MT], Bf[NB];
#pragma unroll
      for (int i = 0; i < MT; ++i) {
        int rl = STRIDE * trA[i] + kh;
        int cl = STRIDE * (tcA[i] * 16 + lm) + kw;
        int g = lg ^ swz(cl);
        Af[i] = *(const s8v*)(lds + (rl * IC + cl) * ROWB + g * 16);
      }
#pragma unroll
      for (int j = 0; j < NB; ++j)
        Bf[j] = as_s8v(wfp[(ng * NB + j) * 64 + lane]);
#pragma unroll
      for (int i = 0; i < MT; ++i)
#pragma unroll
        for (int j = 0; j < NB; ++j)
          acc[i][j] = __builtin_amdgcn_mfma_f32_16x16x32_bf16(Af[i], Bf[j], acc[i][j], 0, 0, 0);
    }

    if (ksl + 1 < NSL) {
      __syncthreads();
      stage_commit<NLD, NTHR, NGRAN, IC, ROWB, HAS_BN>(lds, bn_a, bn_b, ih0, iw0, HI, WI, ksl + 1, tid, stgN);
      __syncthreads();
    }
  }

  const size_t obase = (size_t)n * HO * WO * COUT;
  float sacc[NB], qacc[NB];
#pragma unroll
  for (int j = 0; j < NB; ++j) { sacc[j] = 0.f; qacc[j] = 0.f; }

#pragma unroll
  for (int i = 0; i < MT; ++i) {
#pragma unroll
    for (int j = 0; j < NB; ++j) {
      int oc = (ng * NB + j) * 16 + lm;
#pragma unroll
      for (int r = 0; r < 4; ++r) {
        int oh = oh0 + trA[i];
        int ow = ow0 + tcA[i] * 16 + lg * 4 + r;
        float v = acc[i][j][r];
        if constexpr (HAS_STATS) { sacc[j] += v; qacc[j] += v * v; }
        out[obase + (size_t)(oh * WO + ow) * COUT + oc] = __float2bfloat16(v);
      }
    }
  }

  if constexpr (HAS_STATS) {
    __shared__ float sred[2 * COUT];
    for (int i = tid; i < 2 * COUT; i += NTHR) sred[i] = 0.f;
    __syncthreads();
#pragma unroll
    for (int j = 0; j < NB; ++j) {
      int oc = (ng * NB + j) * 16 + lm;
      atomicAdd(&sred[oc], sacc[j]);
      atomicAdd(&sred[COUT + oc], qacc[j]);
    }
    __syncthreads();
    for (int i = tid; i < 2 * COUT; i += NTHR) atomicAdd(&stats[i], sred[i]);
  }
}

// ---------------- deconv (ConvTranspose2d k4 s2 p1, 64->32) via 16x16x32 ----------------
__global__ __launch_bounds__(256)
void deconv16_k(const bf16* __restrict__ in, const uint4* __restrict__ wf5,
                bf16* __restrict__ out, const float* __restrict__ a4,
                const float* __restrict__ b4, float* __restrict__ stats) {
  constexpr int IR = 6, IC = 50, INB = IR * IC * 128;
  __shared__ __align__(16) char lds[INB];
  __shared__ float sred[64];
  const int tid = threadIdx.x;
  const int lane = tid & 63, wv = tid >> 6;
  const int lm = lane & 15, lg = lane >> 4;
  const int n = blockIdx.x / 6;
  const int qh0 = (blockIdx.x % 6) * 4;
  const size_t ibase = (size_t)n * HW2 * 64;

  for (int idx = tid; idx < 64; idx += 256) sred[idx] = 0.f;

  for (int idx = tid; idx < IR * IC * 8; idx += 256) {
    int h8 = idx & 7; int icl = (idx >> 3) % IC; int ihl = (idx >> 3) / IC;
    int ih = qh0 - 1 + ihl, iw = -1 + icl;
    uint4 v = make_uint4(0u, 0u, 0u, 0u);
    if (ih >= 0 && ih < H2 && iw >= 0 && iw < W2) {
      v = *(const uint4*)(in + ibase + ((size_t)(ih * W2 + iw)) * 64 + h8 * 8);
      v = bn8<true>(v, a4, b4, h8 * 8);
    }
    int bbyte = (ihl * IC + icl) * 128 + h8 * 16;
    bbyte ^= (icl & 7) << 4;
    *(uint4*)(lds + bbyte) = v;
  }
  __syncthreads();

  int trA[3], tcA[3];
#pragma unroll
  for (int i = 0; i < 3; ++i) { int mt = wv * 3 + i; trA[i] = mt / 3; tcA[i] = mt % 3; }

  float sacc[2], qacc[2];
  sacc[0] = sacc[1] = qacc[0] = qacc[1] = 0.f;

  for (int p = 0; p < 4; ++p) {
    const int ph = p >> 1, pw = p & 1;
    f4v acc[3][2];
#pragma unroll
    for (int i = 0; i < 3; ++i)
#pragma unroll
      for (int j = 0; j < 2; ++j)
#pragma unroll
        for (int r = 0; r < 4; ++r) acc[i][j][r] = 0.f;
#pragma unroll
    for (int ks = 0; ks < 8; ++ks) {
      int t = ks >> 2, u = (ks >> 1) & 1, cb = ks & 1;
      s8v Af[3], Bf[2];
#pragma unroll
      for (int i = 0; i < 3; ++i) {
        int rl = trA[i] + t + ph;
        int cl = tcA[i] * 16 + lm + u + pw;
        int bbyte = (rl * IC + cl) * 128 + cb * 64 + lg * 16;
        bbyte ^= (cl & 7) << 4;
        Af[i] = *(const s8v*)(lds + bbyte);
      }
#pragma unroll
      for (int j = 0; j < 2; ++j)
        Bf[j] = as_s8v(wf5[p * 1024 + (ks * 2 + j) * 64 + lg * 16 + lm]);
#pragma unroll
      for (int i = 0; i < 3; ++i)
#pragma unroll
        for (int j = 0; j < 2; ++j)
          acc[i][j] = __builtin_amdgcn_mfma_f32_16x16x32_bf16(Af[i], Bf[j], acc[i][j], 0, 0, 0);
    }
#pragma unroll
    for (int i = 0; i < 3; ++i) {
#pragma unroll
      for (int j = 0; j < 2; ++j) {
        int oc = j * 16 + lm;
#pragma unroll
        for (int r = 0; r < 4; ++r) {
          int qh = qh0 + trA[i];
          int qw = tcA[i] * 16 + lg * 4 + r;
          int oh = 2 * qh + ph, ow = 2 * qw + pw;
          float v = acc[i][j][r];
          sacc[j] += v; qacc[j] += v * v;
          out[((size_t)n * HW + oh * Ww + ow) * 32 + oc] = __float2bfloat16(v);
        }
      }
    }
  }

  __syncthreads();
#pragma unroll
  for (int j = 0; j < 2; ++j) {
    int oc = j * 16 + lm;
    atomicAdd(&sred[oc], sacc[j]);
    atomicAdd(&sred[32 + oc], qacc[j]);
  }
  __syncthreads();
  for (int i = tid; i < 64; i += 256) atomicAdd(&stats[i], sred[i]);
}

// ---------------- BN finalize ----------------
__global__ void bnfin_k(const float* __restrict__ sums, const float* __restrict__ gamma,
                        const float* __restrict__ beta, float* __restrict__ ab, int C, float invCnt) {
  int c = blockIdx.x * blockDim.x + threadIdx.x;
  if (c >= C) return;
  float mean = sums[c] * invCnt;
  float var = sums[C + c] * invCnt - mean * mean;
  float a = gamma[c] * rsqrtf(var + 1e-5f);
  ab[c] = a;
  ab[C + c] = beta[c] - mean * a;
}

// ---------------- conv6 (32->1, 3x3, fused bn5) ----------------
__global__ __launch_bounds__(256)
void conv6_k(const bf16* __restrict__ y5, const float* __restrict__ w6,
             const float* __restrict__ b6, const float* __restrict__ a5,
             const float* __restrict__ bb5, float* __restrict__ y6) {
  int o = blockIdx.x * 256 + threadIdx.x;
  if (o >= Nn * HW) return;
  int hw = o % HW; int n = o / HW;
  int h = hw / Ww, w = hw % Ww;
  float acc = b6[0];
  for (int kh = 0; kh < 3; ++kh) {
    int ih = h - 1 + kh; if (ih < 0 || ih >= Hh) continue;
    for (int kw = 0; kw < 3; ++kw) {
      int iw = w - 1 + kw; if (iw < 0 || iw >= Ww) continue;
      const bf16* p = y5 + ((size_t)n * HW + ih * Ww + iw) * 32;
      int khw = kh * 3 + kw;
#pragma unroll
      for (int c8 = 0; c8 < 4; ++c8) {
        union { uint4 u; unsigned short hh[8]; } X;
        X.u = *(const uint4*)(p + c8 * 8);
#pragma unroll
        for (int i = 0; i < 8; ++i) {
          int c = c8 * 8 + i;
          float f = fmaxf(bf2f(X.hh[i]) * a5[c] + bb5[c], 0.f);
          acc += f * w6[c * 9 + khw];
        }
      }
    }
  }
  y6[o] = acc;
}

// ---------------- DAP ----------------
__global__ __launch_bounds__(256)
void dap_k(const float* __restrict__ y6, const float* __restrict__ dap, float* __restrict__ out) {
  int o = blockIdx.x * 256 + threadIdx.x;
  if (o >= Bb * DD * HW) return;
  int hw = o % HW;
  int e = (o / HW) % DD;
  int b = o / (HW * DD);
  float s = 0.f;
#pragma unroll 7
  for (int d = 0; d < DD; ++d) s += dap[e * DD + d] * y6[((size_t)(b * DD + d)) * HW + hw];
  out[o] = s;
}

// ---------------- host launch ----------------
extern "C" void kernel_launch(void* const* d_in, const int* in_sizes, int n_in,
                              void* d_out, int out_size, void* d_ws, size_t ws_size,
                              hipStream_t stream) {
  const float* f1 = (const float*)d_in[0];
  const float* f2 = (const float*)d_in[1];
  const float* coords = (const float*)d_in[2];
  const float* w1 = (const float*)d_in[3];
  const float* g1 = (const float*)d_in[4];
  const float* b1 = (const float*)d_in[5];
  const float* w2 = (const float*)d_in[6];
  const float* g2 = (const float*)d_in[7];
  const float* b2 = (const float*)d_in[8];
  const float* w3 = (const float*)d_in[9];
  const float* g3 = (const float*)d_in[10];
  const float* b3 = (const float*)d_in[11];
  const float* w4 = (const float*)d_in[12];
  const float* g4 = (const float*)d_in[13];
  const float* b4 = (const float*)d_in[14];
  const float* w5 = (const float*)d_in[15];
  const float* g5 = (const float*)d_in[16];
  const float* b5 = (const float*)d_in[17];
  const float* w6 = (const float*)d_in[18];
  const float* b6 = (const float*)d_in[19];
  const float* dap = (const float*)d_in[20];
  float* out = (float*)d_out;
  char* ws = (char*)d_ws;
  if (ws_size < WS_NEEDED) return;

  uint4* wf1a = (uint4*)(ws + off_wf1a);
  uint4* wf1b = (uint4*)(ws + off_wf1b);
  uint4* wf3 = (uint4*)(ws + off_wf3);
  uint4* wf2 = (uint4*)(ws + off_wf2);
  uint4* wf4 = (uint4*)(ws + off_wf4);
  uint4* wf5 = (uint4*)(ws + off_wf5);
  bf16* f1t = (bf16*)(ws + off_f1t);
  float* y1a = (float*)(ws + off_y1a);
  float* f2t = (float*)(ws + off_f2t);
  bf16* f2s = (bf16*)(ws + off_f2s);
  bf16* y1 = (bf16*)(ws + off_y1);
  bf16* y2 = (bf16*)(ws + off_y2);
  bf16* y3 = (bf16*)(ws + off_y3);
  bf16* y4 = (bf16*)(ws + off_y4);
  bf16* y5 = (bf16*)(ws + off_y5);
  float* y6 = (float*)(ws + off_y6);
  float* st0 = (float*)(ws + off_stats) + 0 * 512;
  float* st1 = (float*)(ws + off_stats) + 1 * 512;
  float* st2 = (float*)(ws + off_stats) + 2 * 512;
  float* st3 = (float*)(ws + off_stats) + 3 * 512;
  float* st4 = (float*)(ws + off_stats) + 4 * 512;

  zero_k<<<10, 256, 0, stream>>>((float*)(ws + off_stats), 2560);

  tr_f2_k<<<576, 256, 0, stream>>>(f2, f2t);
  tr_f1_k<<<576, 256, 0, stream>>>(f1, f1t);
  prep32_k<<<54, 256, 0, stream>>>(w1, wf1a, 3, 256, 0);
  prep32_k<<<54, 256, 0, stream>>>(w1, wf1b, 3, 256, 128);
  prep32_k<<<72, 256, 0, stream>>>(w3, wf3, 4, 128, 0);
  prep16_k<<<54, 256, 0, stream>>>(w2, wf2, 8, 96, 3, 32, 1);
  prep16_k<<<36, 256, 0, stream>>>(w4, wf4, 4, 128, 4, 32, 1);
  prep_w5_k<<<16, 256, 0, stream>>>(w5, wf5);

  sample_k<<<3528, 256, 0, stream>>>(f2t, coords, f2s);

  // conv1 f1-half (shared across 49 displacements), f32 NHWC out
  conv32_k<96, 3, 2, 3, 4, 2, 128, true, false, false, false><<<36, 256, 0, stream>>>(
      f1t, wf1a, y1a, nullptr, nullptr, nullptr, nullptr, 2, Hh, Ww, 1);
  // conv1 f2-half + base, fused BN1 stats
  conv32_k<96, 3, 2, 3, 4, 2, 128, false, true, false, true><<<1764, 256, 0, stream>>>(
      f2s, wf1b, y1, y1a, nullptr, nullptr, st0, Nn, Hh, Ww, DD);
  bnfin_k<<<1, 256, 0, stream>>>(st0, g1, b1, st0 + 256, 96, 1.f / (98.f * 4608.f));

  // conv2 stride 2 (bn1 fused on input staging), fused BN2 stats
  conv16_k<128, 8, 3, 4, 2, 3, 2, 96, true, true><<<1176, 256, 0, stream>>>(
      y1, wf2, y2, st0 + 256, st0 + 256 + 96, st1, Nn, H2, W2, Hh, Ww);
  bnfin_k<<<1, 256, 0, stream>>>(st1, g2, b2, st1 + 256, 128, 1.f / (98.f * 1152.f));

  // conv3 (bn2 fused), fused BN3 stats
  conv32_k<128, 4, 3, 2, 2, 3, 128, false, false, true, true><<<588, 256, 0, stream>>>(
      y2, wf3, y3, nullptr, st1 + 256, st1 + 256 + 128, st2, Nn, H2, W2, 1);
  bnfin_k<<<1, 256, 0, stream>>>(st2, g3, b3, st2 + 256, 128, 1.f / (98.f * 1152.f));

  // conv4 (bn3 fused), fused BN4 stats
  conv16_k<64, 4, 3, 4, 4, 3, 1, 128, true, true><<<588, 256, 0, stream>>>(
      y3, wf4, y4, st2 + 256, st2 + 256 + 128, st3, Nn, H2, W2, H2, W2);
  bnfin_k<<<1, 256, 0, stream>>>(st3, g4, b4, st3 + 256, 64, 1.f / (98.f * 1152.f));

  // deconv (bn4 fused), fused BN5 stats
  deconv16_k<<<588, 256, 0, stream>>>(y4, wf5, y5, st3 + 256, st3 + 256 + 64, st4);
  bnfin_k<<<1, 256, 0, stream>>>(st4, g5, b5, st4 + 256, 32, 1.f / (98.f * 4608.f));

  // conv6 (bn5 fused) + bias -> f32
  conv6_k<<<1764, 256, 0, stream>>>(y5, w6, b6, st4 + 256, st4 + 256 + 32, y6);

  // DAP
  dap_k<<<1764, 256, 0, stream>>>(y6, dap, out);
}